// Round 7
// baseline (717.257 us; speedup 1.0000x reference)
//
#include <hip/hip_runtime.h>

#define N_NODES 100000
#define N_EDGES 1600000
#define N_GRAPHS 1024
#define HID 128
#define LAYERS 4
#define LN_EPS 1e-5f
#define GTS 136      // ushort row stride for bf16 LDS planes (16B-aligned)
#define HLS 132      // f32 row stride for h stash (2-way bank alias = free)
#define NB_PROJ 50000
#define NB_WCONV 512
#define NBUCK 1563     // ceil(N_NODES/64) buckets of 64 nodes
#define BCAP 2048      // LDS staging capacity (mean 1024, sd 32 -> +32 sigma)
#define NSTREAM 8      // append streams per bucket (blockIdx&7 ~ XCD id)
#define CURPAD 32      // ints: one cursor per 128B line
#define EPB 4096       // edges per hist/binscat block (16/thread)
#define NB_BS 391      // ceil(N_EDGES/EPB)

// R2: global atomics write ~32B to HBM each -> minimize COUNT.
// R4/R5: NU not VALU-bound, not pipeline-depth-bound.
// R6 lesson: h-stash cut FETCH 237->216MB but its 8.5KB LDS cut blocks
// 8->6 (occ 72->56%) -- byte win canceled by wave loss. R7: same stash,
// zero LDS cost: h rows ride phases 1-2 in 8 VGPRs, land in the gt
// region (dead after phase 2) at the top of phase 3; stats relocate to
// the t1 region (dead after phase-3 MFMA). LDS back to 17408 -> 8
// blocks/CU, keeping R6's traffic.

typedef __attribute__((ext_vector_type(8))) short bf16x8;
typedef __attribute__((ext_vector_type(4))) float f32x4;
typedef __attribute__((ext_vector_type(2))) float f32x2;

__device__ __forceinline__ unsigned short f2bf(float x) {
    unsigned v = __float_as_uint(x);
    return (unsigned short)((v + 0x7fffu + ((v >> 16) & 1u)) >> 16);
}
__device__ __forceinline__ float bfval(unsigned short u) {
    return __uint_as_float((unsigned)u << 16);
}
// packed-f32 ops (CDNA2+): hipcc never forms these from scalar code.
__device__ __forceinline__ f32x2 pk_fma(f32x2 a, f32x2 b, f32x2 c) {
    f32x2 d;
    asm("v_pk_fma_f32 %0, %1, %2, %3" : "=v"(d) : "v"(a), "v"(b), "v"(c));
    return d;
}
__device__ __forceinline__ f32x2 pk_add(f32x2 a, f32x2 b) {
    f32x2 d;
    asm("v_pk_add_f32 %0, %1, %2" : "=v"(d) : "v"(a), "v"(b));
    return d;
}

// ------- prep: input projection + MFMA weight pre-swizzle ------------
__global__ __launch_bounds__(256) void k_prep(
    const float* __restrict__ x, const float* __restrict__ inW,
    const float* __restrict__ inb, float* __restrict__ h,
    unsigned short* __restrict__ hb,
    const float* __restrict__ w1, const float* __restrict__ w2,
    unsigned short* __restrict__ wf_hi, unsigned short* __restrict__ wf_lo) {
    if (blockIdx.x < NB_PROJ) {
        int idx = blockIdx.x * 256 + threadIdx.x;  // N_NODES*HID exact
        int n = idx >> 7, c = idx & 127;
        const float* xr = x + n * 7;
        float s = inb[c];
#pragma unroll
        for (int k = 0; k < 7; ++k) s += xr[k] * inW[k * HID + c];
        h[idx] = s;
        hb[idx] = f2bf(s);
    } else {
        int idx = (blockIdx.x - NB_PROJ) * 256 + threadIdx.x;  // LAYERS*2*16384
        int wid = idx >> 14;
        int layer = wid >> 1, which = wid & 1;
        int within = idx & 16383;
        int nt = within >> 11;
        int ks = (within >> 9) & 3;
        int ln = (within >> 3) & 63;
        int j = within & 7;
        const float* W = (which ? w2 : w1) + layer * HID * HID;
        int k = ks * 32 + (ln >> 4) * 8 + j;
        int n = nt * 16 + (ln & 15);
        float v = W[k * HID + n];
        unsigned short hi = f2bf(v);
        wf_hi[idx] = hi;
        wf_lo[idx] = f2bf(v - bfval(hi));
    }
}

// ------- CSR build: LDS-aggregated (bucket,stream) histogram ---------
__global__ __launch_bounds__(256) void k_hist(
    const int* __restrict__ ei, int* __restrict__ cnt2) {
    __shared__ int hcnt[NBUCK];
    const int t = threadIdx.x;
    for (int i = t; i < NBUCK; i += 256) hcnt[i] = 0;
    __syncthreads();
    const int e0 = blockIdx.x * EPB;
    const int eend = (e0 + EPB < N_EDGES) ? e0 + EPB : N_EDGES;
#pragma unroll
    for (int k = 0; k < 16; ++k) {
        const int e = e0 + k * 256 + t;
        if (e < eend) atomicAdd(&hcnt[ei[N_EDGES + e] >> 6], 1);
    }
    __syncthreads();
    const int sgrp = blockIdx.x & 7;
    for (int i = t; i < NBUCK; i += 256) {
        const int c = hcnt[i];
        if (c) atomicAdd(&cnt2[((i << 3) + sgrp) << 5], c);
    }
}

// ------- CSR build: bucket scan -> bucket_base + segment bases -------
__global__ __launch_bounds__(1024) void k_segscan(
    const int* __restrict__ cnt2, int* __restrict__ pcur,
    int* __restrict__ bucket_base, int* __restrict__ row_ptr) {
    __shared__ int lsum[1024];
    const int t = threadIdx.x;
    const int b0 = 2 * t, b1 = 2 * t + 1;
    int u0 = 0, u1 = 0;
    if (b0 < NBUCK) {
#pragma unroll
        for (int s = 0; s < NSTREAM; ++s) u0 += cnt2[((b0 << 3) + s) << 5];
    }
    if (b1 < NBUCK) {
#pragma unroll
        for (int s = 0; s < NSTREAM; ++s) u1 += cnt2[((b1 << 3) + s) << 5];
    }
    const int v = u0 + u1;
    lsum[t] = v;
    __syncthreads();
    for (int off = 1; off < 1024; off <<= 1) {
        const int u = (t >= off) ? lsum[t - off] : 0;
        __syncthreads();
        lsum[t] += u;
        __syncthreads();
    }
    const int excl = lsum[t] - v;  // exclusive over threads (bucket pairs)
    if (b0 < NBUCK) {
        bucket_base[b0] = excl;
        int run = excl;
#pragma unroll
        for (int s = 0; s < NSTREAM; ++s) {
            const int c = ((b0 << 3) + s) << 5;
            pcur[c] = run;
            run += cnt2[c];
        }
    }
    if (b1 < NBUCK) {
        const int base1 = excl + u0;
        bucket_base[b1] = base1;
        int run = base1;
#pragma unroll
        for (int s = 0; s < NSTREAM; ++s) {
            const int c = ((b1 << 3) + s) << 5;
            pcur[c] = run;
            run += cnt2[c];
        }
    }
    if (t == 0) {
        bucket_base[NBUCK] = N_EDGES;
        row_ptr[N_NODES] = N_EDGES;
    }
}

// -------- CSR build pass 1: chunk-reserved binned append -------------
__global__ __launch_bounds__(256) void k_binscat(
    const int* __restrict__ ei, const float* __restrict__ ea,
    int* __restrict__ pcur, int4* __restrict__ erec) {
    __shared__ int hcnt[NBUCK];
    const int t = threadIdx.x;
    for (int i = t; i < NBUCK; i += 256) hcnt[i] = 0;
    __syncthreads();
    const int e0 = blockIdx.x * EPB;
    const int eend = (e0 + EPB < N_EDGES) ? e0 + EPB : N_EDGES;
#pragma unroll
    for (int k = 0; k < 16; ++k) {
        const int e = e0 + k * 256 + t;
        if (e < eend) atomicAdd(&hcnt[ei[N_EDGES + e] >> 6], 1);
    }
    __syncthreads();
    const int sgrp = blockIdx.x & 7;
    for (int i = t; i < NBUCK; i += 256) {
        const int c = hcnt[i];
        hcnt[i] = c ? atomicAdd(&pcur[((i << 3) + sgrp) << 5], c) : 0;
    }
    __syncthreads();
#pragma unroll
    for (int k = 0; k < 16; ++k) {
        const int e = e0 + k * 256 + t;
        if (e < eend) {
            const int src = ei[e];
            const int dst = ei[N_EDGES + e];
            const float a0 = ea[e * 3 + 0];
            const float a1 = ea[e * 3 + 1];
            const float a2 = ea[e * 3 + 2];
            const int pos = atomicAdd(&hcnt[dst >> 6], 1);  // LDS
            int4 r;
            r.x = src | ((dst & 63) << 20);  // src < 2^17 fits low 20 bits
            r.y = __float_as_int(a0);
            r.z = __float_as_int(a1);
            r.w = __float_as_int(a2);
            erec[pos] = r;
        }
    }
}

// -------- CSR build pass 2: per-bucket LDS sort + row_ptr ------------
__global__ __launch_bounds__(256) void k_bucketsort(
    const int4* __restrict__ erec, const int* __restrict__ bucket_base,
    int* __restrict__ row_ptr, int4* __restrict__ edata) {
    __shared__ int rhist[64];
    __shared__ int lcur[64];
    __shared__ int4 stage[BCAP];
    const int b = blockIdx.x;
    const int nb0 = b << 6;
    const int nrows = (nb0 + 64 <= N_NODES) ? 64 : (N_NODES - nb0);
    const int base = bucket_base[b];
    const int end = bucket_base[b + 1];
    const int cnt = end - base;
    const int t = threadIdx.x;
    if (t < 64) rhist[t] = 0;
    __syncthreads();
    for (int i = t; i < cnt; i += 256)
        atomicAdd(&rhist[(erec[base + i].x >> 20) & 63], 1);
    __syncthreads();
    if (t < 64) {
        const int v = rhist[t];
        int incl = v;
#pragma unroll
        for (int off = 1; off < 64; off <<= 1) {
            const int u = __shfl_up(incl, off);
            if (t >= off) incl += u;
        }
        const int excl = incl - v;
        lcur[t] = excl;
        if (t < nrows) row_ptr[nb0 + t] = base + excl;
    }
    __syncthreads();
    if (cnt <= BCAP) {
        for (int i = t; i < cnt; i += 256) {
            const int4 r = erec[base + i];  // L2-warm re-read
            stage[atomicAdd(&lcur[(r.x >> 20) & 63], 1)] = r;
        }
        __syncthreads();
        for (int i = t; i < cnt; i += 256) {
            int4 r = stage[i];
            r.x &= 0xFFFFF;
            edata[base + i] = r;
        }
    } else {
        // statistically unreachable fallback (cnt mean 1024, sd 32)
        for (int i = t; i < cnt; i += 256) {
            const int4 r = erec[base + i];
            const int pos = base + atomicAdd(&lcur[(r.x >> 20) & 63], 1);
            int4 o = r;
            o.x = r.x & 0xFFFFF;
            edata[pos] = o;
        }
    }
}

// -- phase-1 edge macros (macros only: outlined helpers spill) --------
#define FLUSHSTEP {                                                            \
    if (rcur == 0)      { a0v = acc2; rnext = rp2; }                           \
    else if (rcur == 1) { a1v = acc2; rnext = rp3; }                           \
    else                { a2v = acc2; rnext = 0x7fffffff; }                    \
    acc2[0] = 0.f; acc2[1] = 0.f; ++rcur; }

#define EL(JJ)                                                                 \
    const int s##JJ = __builtin_amdgcn_readlane(cS, j + JJ);                   \
    const unsigned gq##JJ = *(const unsigned*)(hbin + (long)s##JJ * HID + c2);

#define EC(JJ) {                                                               \
    const int gi = t + j + (JJ);                                               \
    while (gi >= rnext) FLUSHSTEP                                              \
    const f32x4 qq = attAB[j + (JJ)];                                          \
    const f32x2 pC = attC[j + (JJ)];                                           \
    f32x2 pA; pA[0] = qq[0]; pA[1] = qq[1];                                    \
    f32x2 pB; pB[0] = qq[2]; pB[1] = qq[3];                                    \
    f32x2 g2; g2[0] = __uint_as_float(gq##JJ << 16);                           \
    g2[1] = __uint_as_float(gq##JJ & 0xffff0000u);                             \
    const f32x2 m2 = pk_fma(pC, ew2v, pk_fma(pB, ew1v, pk_fma(pA, ew0v,        \
                            pk_add(g2, ebv2))));                               \
    f32x2 r2; r2[0] = fmaxf(m2[0], 0.f); r2[1] = fmaxf(m2[1], 0.f);            \
    acc2 = pk_add(acc2, r2); }

// ROW_OUT: capture the h row pair into registers (HV) for phase 3;
// write gt planes for phase-2 MFMA.
#define ROW_OUT(R, AV, HV) {                                                   \
    const float2 hv = *(const float2*)(h + (long)(nb + (R)) * HID + c2);       \
    HV[0] = hv.x; HV[1] = hv.y;                                                \
    const float gx = hv.x + (AV)[0], gy = hv.y + (AV)[1];                      \
    const unsigned short hx = f2bf(gx), hy = f2bf(gy);                         \
    const unsigned short lx = f2bf(gx - bfval(hx)), ly = f2bf(gy - bfval(hy)); \
    *(unsigned*)&gt_hi[(r0 + (R)) * GTS + c2] = (unsigned)hx | ((unsigned)hy << 16); \
    *(unsigned*)&gt_lo[(r0 + (R)) * GTS + c2] = (unsigned)lx | ((unsigned)ly << 16); }

#define T1_OUT(CC, NT) {                                                       \
    const float4 bv = *(const float4*)(b1 + (NT) * 16 + q4);                   \
    const float v0 = fmaxf(CC[0] + bv.x, 0.f);                                 \
    const float v1 = fmaxf(CC[1] + bv.y, 0.f);                                 \
    const float v2 = fmaxf(CC[2] + bv.z, 0.f);                                 \
    const float v3 = fmaxf(CC[3] + bv.w, 0.f);                                 \
    const unsigned short h0_ = f2bf(v0), h1_ = f2bf(v1), h2_ = f2bf(v2), h3_ = f2bf(v3); \
    const unsigned short l0_ = f2bf(v0 - bfval(h0_)), l1_ = f2bf(v1 - bfval(h1_)); \
    const unsigned short l2_ = f2bf(v2 - bfval(h2_)), l3_ = f2bf(v3 - bfval(h3_)); \
    *(uint2*)&t1_hi[ln15 * GTS + (NT) * 16 + q4] =                             \
        make_uint2((unsigned)h0_ | ((unsigned)h1_ << 16), (unsigned)h2_ | ((unsigned)h3_ << 16)); \
    *(uint2*)&t1_lo[ln15 * GTS + (NT) * 16 + q4] =                             \
        make_uint2((unsigned)l0_ | ((unsigned)l1_ << 16), (unsigned)l2_ | ((unsigned)l3_ << 16)); }

// ------- fused gather-aggregate + MFMA MLP + residual + layernorm ----
__global__ __launch_bounds__(256, 8) void k_node_update(
    const int4* __restrict__ edata, const int* __restrict__ row_ptr,
    const float* __restrict__ eW, const float* __restrict__ eb,
    float* __restrict__ h, const unsigned short* __restrict__ hbin,
    unsigned short* __restrict__ hbout,
    const unsigned short* __restrict__ w1f_hi, const unsigned short* __restrict__ w1f_lo,
    const unsigned short* __restrict__ w2f_hi, const unsigned short* __restrict__ w2f_lo,
    const float* __restrict__ b1, const float* __restrict__ b2,
    const float* __restrict__ gamma, const float* __restrict__ beta) {
    __shared__ __align__(16) unsigned char smem[17408];
    unsigned short* gt_hi = (unsigned short*)(smem + 0);      // [16][GTS], phases 1-2
    unsigned short* gt_lo = (unsigned short*)(smem + 4352);
    unsigned short* t1_hi = (unsigned short*)(smem + 8704);   // phases 2-3
    unsigned short* t1_lo = (unsigned short*)(smem + 13056);
    float* hstash = (float*)smem;                 // [16][HLS] f32, phase 3 (gt region, dead after ph2)
    float* stats = (float*)(smem + 8704);         // [4][32] f32, phase 3 (t1 region, dead after ph3 MFMA)

    const int wave = threadIdx.x >> 6;
    const int lane = threadIdx.x & 63;
    const int n0 = blockIdx.x * 16;
    const int r0 = wave * 4;
    const int c2 = lane * 2;

    // h rows ride phases 1-2 in registers (8 VGPR), stashed to LDS in ph3
    f32x2 hv_r0, hv_r1, hv_r2, hv_r3;

    // ---- phase 1: gather-aggregate (EL16/EC16 structure) ----
    // per-wave attr slab in the t1 region (dead until phase 2)
    {
        f32x4* attAB = (f32x4*)(smem + 8704 + wave * 1536);        // (a0,a0,a1,a1)
        f32x2* attC  = (f32x2*)(smem + 8704 + wave * 1536 + 1024); // (a2,a2)
        const f32x2 ew0v = *(const f32x2*)(eW + 0 * HID + c2);
        const f32x2 ew1v = *(const f32x2*)(eW + 1 * HID + c2);
        const f32x2 ew2v = *(const f32x2*)(eW + 2 * HID + c2);
        const f32x2 ebv2 = *(const f32x2*)(eb + c2);
        const int nb = n0 + r0;
        const int rp0 = __builtin_amdgcn_readfirstlane(row_ptr[nb + 0]);
        const int rp1 = __builtin_amdgcn_readfirstlane(row_ptr[nb + 1]);
        const int rp2 = __builtin_amdgcn_readfirstlane(row_ptr[nb + 2]);
        const int rp3 = __builtin_amdgcn_readfirstlane(row_ptr[nb + 3]);
        const int rp4 = __builtin_amdgcn_readfirstlane(row_ptr[nb + 4]);

        f32x2 a0v = {0.f, 0.f}, a1v = {0.f, 0.f};
        f32x2 a2v = {0.f, 0.f}, a3v = {0.f, 0.f};
        f32x2 acc2 = {0.f, 0.f};    // running accumulator (current row)
        int rcur = 0;               // current row index (scalar)
        int rnext = rp1;            // next row boundary

        int4 cE = {0, 0, 0, 0}, nE = {0, 0, 0, 0};
        if (rp0 + lane < rp4) cE = edata[rp0 + lane];
        for (int t = rp0; t < rp4; t += 64) {
            const int cnt = (rp4 - t < 64) ? (rp4 - t) : 64;
            // stage current tile's attrs (duplicated pairs) to LDS
            f32x4 dAB;
            dAB[0] = __int_as_float(cE.y); dAB[1] = dAB[0];
            dAB[2] = __int_as_float(cE.z); dAB[3] = dAB[2];
            f32x2 dC;
            dC[0] = __int_as_float(cE.w); dC[1] = dC[0];
            attAB[lane] = dAB;
            attC[lane] = dC;
            const int cS = cE.x;
            __builtin_amdgcn_wave_barrier();  // ds_write -> ds_read order (same wave, in-order LDS)
            if (t + 64 + lane < rp4)  // prefetch next tile (one 16B load)
                nE = edata[t + 64 + lane];
            int j = 0;
            for (; j + 16 <= cnt; j += 16) {
                EL(0) EL(1) EL(2) EL(3) EL(4) EL(5) EL(6) EL(7)
                EL(8) EL(9) EL(10) EL(11) EL(12) EL(13) EL(14) EL(15)
                EC(0) EC(1) EC(2) EC(3) EC(4) EC(5) EC(6) EC(7)
                EC(8) EC(9) EC(10) EC(11) EC(12) EC(13) EC(14) EC(15)
            }
            for (; j + 4 <= cnt; j += 4) {
                EL(0) EL(1) EL(2) EL(3)
                EC(0) EC(1) EC(2) EC(3)
            }
            for (; j < cnt; ++j) {
                EL(0)
                EC(0)
            }
            __builtin_amdgcn_wave_barrier();  // keep next staging below these reads
            cE = nE;
        }
        // tail: running acc belongs to row rcur; rows after it stay zero
        if (rcur == 0)      a0v = acc2;
        else if (rcur == 1) a1v = acc2;
        else if (rcur == 2) a2v = acc2;
        else                a3v = acc2;
        ROW_OUT(0, a0v, hv_r0)
        ROW_OUT(1, a1v, hv_r1)
        ROW_OUT(2, a2v, hv_r2)
        ROW_OUT(3, a3v, hv_r3)
    }
    __syncthreads();

    const int ln15 = lane & 15;
    const int q8 = (lane >> 4) * 8;
    const int q4 = (lane >> 4) * 4;
    const int nt0 = wave * 2, nt1 = nt0 + 1;

    // ---- phase 2: t1 = relu(gt @ w1 + b1) via MFMA (D[hid][node]) ----
    {
        f32x4 c0 = {0.f, 0.f, 0.f, 0.f};
        f32x4 c1 = {0.f, 0.f, 0.f, 0.f};
#pragma unroll
        for (int ks = 0; ks < 4; ++ks) {
            const bf16x8 bh = *(const bf16x8*)&gt_hi[ln15 * GTS + ks * 32 + q8];
            const bf16x8 bl = *(const bf16x8*)&gt_lo[ln15 * GTS + ks * 32 + q8];
            const bf16x8 a0h = *(const bf16x8*)(w1f_hi + (((nt0 * 4 + ks) * 64 + lane) << 3));
            const bf16x8 a0l = *(const bf16x8*)(w1f_lo + (((nt0 * 4 + ks) * 64 + lane) << 3));
            const bf16x8 a1h = *(const bf16x8*)(w1f_hi + (((nt1 * 4 + ks) * 64 + lane) << 3));
            const bf16x8 a1l = *(const bf16x8*)(w1f_lo + (((nt1 * 4 + ks) * 64 + lane) << 3));
            c0 = __builtin_amdgcn_mfma_f32_16x16x32_bf16(a0h, bh, c0, 0, 0, 0);
            c0 = __builtin_amdgcn_mfma_f32_16x16x32_bf16(a0h, bl, c0, 0, 0, 0);
            c0 = __builtin_amdgcn_mfma_f32_16x16x32_bf16(a0l, bh, c0, 0, 0, 0);
            c1 = __builtin_amdgcn_mfma_f32_16x16x32_bf16(a1h, bh, c1, 0, 0, 0);
            c1 = __builtin_amdgcn_mfma_f32_16x16x32_bf16(a1h, bl, c1, 0, 0, 0);
            c1 = __builtin_amdgcn_mfma_f32_16x16x32_bf16(a1l, bh, c1, 0, 0, 0);
        }
        T1_OUT(c0, nt0)
        T1_OUT(c1, nt1)
    }
    __syncthreads();
    // gt region now dead everywhere: stash h rows there for phase 3
    *(float2*)&hstash[(r0 + 0) * HLS + c2] = make_float2(hv_r0[0], hv_r0[1]);
    *(float2*)&hstash[(r0 + 1) * HLS + c2] = make_float2(hv_r1[0], hv_r1[1]);
    *(float2*)&hstash[(r0 + 2) * HLS + c2] = make_float2(hv_r2[0], hv_r2[1]);
    *(float2*)&hstash[(r0 + 3) * HLS + c2] = make_float2(hv_r3[0], hv_r3[1]);

    // ---- phase 3: u = h + relu(t1 @ w2 + b2); h from gt-region stash ----
    {
        f32x4 c0 = {0.f, 0.f, 0.f, 0.f};
        f32x4 c1 = {0.f, 0.f, 0.f, 0.f};
#pragma unroll
        for (int ks = 0; ks < 4; ++ks) {
            const bf16x8 bh = *(const bf16x8*)&t1_hi[ln15 * GTS + ks * 32 + q8];
            const bf16x8 bl = *(const bf16x8*)&t1_lo[ln15 * GTS + ks * 32 + q8];
            const bf16x8 a0h = *(const bf16x8*)(w2f_hi + (((nt0 * 4 + ks) * 64 + lane) << 3));
            const bf16x8 a0l = *(const bf16x8*)(w2f_lo + (((nt0 * 4 + ks) * 64 + lane) << 3));
            const bf16x8 a1h = *(const bf16x8*)(w2f_hi + (((nt1 * 4 + ks) * 64 + lane) << 3));
            const bf16x8 a1l = *(const bf16x8*)(w2f_lo + (((nt1 * 4 + ks) * 64 + lane) << 3));
            c0 = __builtin_amdgcn_mfma_f32_16x16x32_bf16(a0h, bh, c0, 0, 0, 0);
            c0 = __builtin_amdgcn_mfma_f32_16x16x32_bf16(a0h, bl, c0, 0, 0, 0);
            c0 = __builtin_amdgcn_mfma_f32_16x16x32_bf16(a0l, bh, c0, 0, 0, 0);
            c1 = __builtin_amdgcn_mfma_f32_16x16x32_bf16(a1h, bh, c1, 0, 0, 0);
            c1 = __builtin_amdgcn_mfma_f32_16x16x32_bf16(a1h, bl, c1, 0, 0, 0);
            c1 = __builtin_amdgcn_mfma_f32_16x16x32_bf16(a1l, bh, c1, 0, 0, 0);
        }
        // all waves done: stash writes visible, t1 fully consumed
        __syncthreads();
        const int row = n0 + ln15;
        const float4 b20 = *(const float4*)(b2 + nt0 * 16 + q4);
        const float4 b21 = *(const float4*)(b2 + nt1 * 16 + q4);
        const float4 hv0 = *(const float4*)&hstash[ln15 * HLS + nt0 * 16 + q4];
        const float4 hv1 = *(const float4*)&hstash[ln15 * HLS + nt1 * 16 + q4];
        float4 u0, u1;
        u0.x = hv0.x + fmaxf(c0[0] + b20.x, 0.f);
        u0.y = hv0.y + fmaxf(c0[1] + b20.y, 0.f);
        u0.z = hv0.z + fmaxf(c0[2] + b20.z, 0.f);
        u0.w = hv0.w + fmaxf(c0[3] + b20.w, 0.f);
        u1.x = hv1.x + fmaxf(c1[0] + b21.x, 0.f);
        u1.y = hv1.y + fmaxf(c1[1] + b21.y, 0.f);
        u1.z = hv1.z + fmaxf(c1[2] + b21.z, 0.f);
        u1.w = hv1.w + fmaxf(c1[3] + b21.w, 0.f);
        float s = u0.x + u0.y + u0.z + u0.w + u1.x + u1.y + u1.z + u1.w;
        float s2 = u0.x * u0.x + u0.y * u0.y + u0.z * u0.z + u0.w * u0.w +
                   u1.x * u1.x + u1.y * u1.y + u1.z * u1.z + u1.w * u1.w;
        s += __shfl_xor(s, 16); s2 += __shfl_xor(s2, 16);
        s += __shfl_xor(s, 32); s2 += __shfl_xor(s2, 32);
        if (lane < 16) {
            stats[wave * 32 + lane * 2 + 0] = s;
            stats[wave * 32 + lane * 2 + 1] = s2;
        }
        __syncthreads();
        const float S  = stats[0 * 32 + ln15 * 2] + stats[1 * 32 + ln15 * 2] +
                         stats[2 * 32 + ln15 * 2] + stats[3 * 32 + ln15 * 2];
        const float S2 = stats[0 * 32 + ln15 * 2 + 1] + stats[1 * 32 + ln15 * 2 + 1] +
                         stats[2 * 32 + ln15 * 2 + 1] + stats[3 * 32 + ln15 * 2 + 1];
        const float mu = S * (1.f / HID);
        const float var = S2 * (1.f / HID) - mu * mu;
        const float inv = rsqrtf(var + LN_EPS);
        const float4 gm0 = *(const float4*)(gamma + nt0 * 16 + q4);
        const float4 gm1 = *(const float4*)(gamma + nt1 * 16 + q4);
        const float4 bt0 = *(const float4*)(beta + nt0 * 16 + q4);
        const float4 bt1 = *(const float4*)(beta + nt1 * 16 + q4);
        float4 o0, o1;
        o0.x = (u0.x - mu) * inv * gm0.x + bt0.x;
        o0.y = (u0.y - mu) * inv * gm0.y + bt0.y;
        o0.z = (u0.z - mu) * inv * gm0.z + bt0.z;
        o0.w = (u0.w - mu) * inv * gm0.w + bt0.w;
        o1.x = (u1.x - mu) * inv * gm1.x + bt1.x;
        o1.y = (u1.y - mu) * inv * gm1.y + bt1.y;
        o1.z = (u1.z - mu) * inv * gm1.z + bt1.z;
        o1.w = (u1.w - mu) * inv * gm1.w + bt1.w;
        *(float4*)(h + (long)row * HID + nt0 * 16 + q4) = o0;
        *(float4*)(h + (long)row * HID + nt1 * 16 + q4) = o1;
        *(uint2*)(hbout + (long)row * HID + nt0 * 16 + q4) =
            make_uint2((unsigned)f2bf(o0.x) | ((unsigned)f2bf(o0.y) << 16),
                       (unsigned)f2bf(o0.z) | ((unsigned)f2bf(o0.w) << 16));
        *(uint2*)(hbout + (long)row * HID + nt1 * 16 + q4) =
            make_uint2((unsigned)f2bf(o1.x) | ((unsigned)f2bf(o1.y) << 16),
                       (unsigned)f2bf(o1.z) | ((unsigned)f2bf(o1.w) << 16));
    }
}

// -------- global mean pool: segmented reduction (batch is sorted) ----
__global__ __launch_bounds__(128) void k_pool(
    const float* __restrict__ h, const int* __restrict__ batch,
    float* __restrict__ sums, float* __restrict__ cnt) {
    const int c = threadIdx.x;
    const int n0 = blockIdx.x * 64;
    if (n0 >= N_NODES) return;
    const int nend = min(n0 + 64, N_NODES);
    int cur = batch[n0];
    float acc = 0.f;
    int runlen = 0;
    for (int n = n0; n < nend; ++n) {
        const int b = batch[n];
        if (b != cur) {
            atomicAdd(&sums[(long)cur * HID + c], acc);
            if (c == 0) atomicAdd(&cnt[cur], (float)runlen);
            acc = 0.f;
            runlen = 0;
            cur = b;
        }
        acc += h[(long)n * HID + c];
        ++runlen;
    }
    atomicAdd(&sums[(long)cur * HID + c], acc);
    if (c == 0) atomicAdd(&cnt[cur], (float)runlen);
}

// ---------------- head: 1 block per graph ----------------------------
__global__ __launch_bounds__(128) void k_head(
    const float* __restrict__ sums, const float* __restrict__ cnt,
    const float* __restrict__ fcW1, const float* __restrict__ fcb1,
    const float* __restrict__ fcW2, const float* __restrict__ fcb2,
    const float* __restrict__ fcW3, const float* __restrict__ fcb3,
    float* __restrict__ out) {
    __shared__ float p[HID];
    __shared__ float o1[HID];
    __shared__ float o2[64];
    const int g = blockIdx.x, t = threadIdx.x;
    const float c = fmaxf(cnt[g], 1.0f);
    p[t] = sums[g * HID + t] / c;
    __syncthreads();
    float s = fcb1[t];
    for (int k = 0; k < HID; ++k) s += p[k] * fcW1[k * HID + t];
    o1[t] = fmaxf(s, 0.f);
    __syncthreads();
    if (t < 64) {
        float s2 = fcb2[t];
        for (int k = 0; k < HID; ++k) s2 += o1[k] * fcW2[k * 64 + t];
        o2[t] = fmaxf(s2, 0.f);
    }
    __syncthreads();
    if (t < 64) {
        float v = o2[t] * fcW3[t];
#pragma unroll
        for (int off = 32; off > 0; off >>= 1) v += __shfl_down(v, off);
        if (t == 0) out[g] = v + fcb3[0];
    }
}

extern "C" void kernel_launch(void* const* d_in, const int* in_sizes, int n_in,
                              void* d_out, int out_size, void* d_ws, size_t ws_size,
                              hipStream_t stream) {
    const float* x    = (const float*)d_in[0];
    const int*   ei   = (const int*)d_in[1];
    const float* ea   = (const float*)d_in[2];
    const int*   batch= (const int*)d_in[3];
    const float* inW  = (const float*)d_in[4];
    const float* inb  = (const float*)d_in[5];
    const float* edgeW= (const float*)d_in[6];
    const float* edgeb= (const float*)d_in[7];
    const float* w1   = (const float*)d_in[8];
    const float* b1   = (const float*)d_in[9];
    const float* w2   = (const float*)d_in[10];
    const float* b2   = (const float*)d_in[11];
    const float* gamma= (const float*)d_in[12];
    const float* beta = (const float*)d_in[13];
    const float* fcW1 = (const float*)d_in[14];
    const float* fcb1 = (const float*)d_in[15];
    const float* fcW2 = (const float*)d_in[16];
    const float* fcb2 = (const float*)d_in[17];
    const float* fcW3 = (const float*)d_in[18];
    const float* fcb3 = (const float*)d_in[19];
    float* out = (float*)d_out;

    // workspace layout (16B-aligned blocks first): ~133 MB
    int4*  edata = (int4*)d_ws;                                        // 25.6 MB AoS {src,a0,a1,a2}
    float* h     = (float*)(edata + (size_t)N_EDGES);                  // 51.2 MB
    unsigned short* hb0 = (unsigned short*)(h + (size_t)N_NODES * HID);// 25.6 MB
    unsigned short* hb1 = hb0 + (size_t)N_NODES * HID;                 // 25.6 MB
    unsigned short* wf_hi = hb1 + (size_t)N_NODES * HID;               // 256 KB
    unsigned short* wf_lo = wf_hi + LAYERS * 2 * 16384;                // 256 KB
    int*    row_ptr = (int*)(wf_lo + LAYERS * 2 * 16384);              // 100001 ints
    // 128B-align the padded cursor/counter arrays
    int*    pcur    = (int*)(((size_t)(row_ptr + (N_NODES + 1)) + 127) & ~(size_t)127);
    //                NBUCK*8 segment cursors, CURPAD ints apart       // 1.6 MB (written by segscan)
    int*    bucket_base = pcur + NBUCK * NSTREAM * CURPAD;             // 1564 ints
    // zero-init region (single memset): cnt2, sums, cnt
    int*    cnt2    = (int*)(((size_t)(bucket_base + NBUCK + 1) + 127) & ~(size_t)127);
    float*  sums    = (float*)(cnt2 + NBUCK * NSTREAM * CURPAD);       // 512 KB
    float*  cnt     = sums + (size_t)N_GRAPHS * HID;
    const size_t zbytes = (size_t)NBUCK * NSTREAM * CURPAD * sizeof(int) +
                          ((size_t)N_GRAPHS * HID + N_GRAPHS) * sizeof(float);
    // pass-1 record buffer aliases hb1: 1.6M * 16B == 100000*128*2B == 25.6 MB.
    // Segments tile the CSR range exactly (cnt2-derived bases), so erec is
    // CSR-contiguous: no growth, no overflow. hb1 is dead until
    // k_node_update layer 0 writes it (stream-ordered after k_bucketsort).
    int4*   erec    = (int4*)hb1;

    hipMemsetAsync(cnt2, 0, zbytes, stream);

    k_prep<<<NB_PROJ + NB_WCONV, 256, 0, stream>>>(x, inW, inb, h, hb0,
                                                   w1, w2, wf_hi, wf_lo);

    // CSR build (once per launch, reused across 4 layers)
    k_hist<<<NB_BS, 256, 0, stream>>>(ei, cnt2);
    k_segscan<<<1, 1024, 0, stream>>>(cnt2, pcur, bucket_base, row_ptr);
    k_binscat<<<NB_BS, 256, 0, stream>>>(ei, ea, pcur, erec);
    k_bucketsort<<<NBUCK, 256, 0, stream>>>(erec, bucket_base, row_ptr, edata);

    unsigned short* hbin = hb0;
    unsigned short* hbout = hb1;
    for (int l = 0; l < LAYERS; ++l) {
        k_node_update<<<N_NODES / 16, 256, 0, stream>>>(
            edata, row_ptr, edgeW + l * 3 * HID, edgeb + l * HID,
            h, hbin, hbout,
            wf_hi + (l * 2 + 0) * 16384, wf_lo + (l * 2 + 0) * 16384,
            wf_hi + (l * 2 + 1) * 16384, wf_lo + (l * 2 + 1) * 16384,
            b1 + l * HID, b2 + l * HID, gamma + l * HID, beta + l * HID);
        unsigned short* tmp = hbin; hbin = hbout; hbout = tmp;
    }
    // final h is in-place in `h` (fp32)

    k_pool<<<(N_NODES + 63) / 64, 128, 0, stream>>>(h, batch, sums, cnt);
    k_head<<<N_GRAPHS, 128, 0, stream>>>(sums, cnt, fcW1, fcb1, fcW2, fcb2,
                                         fcW3, fcb3, out);
}

// Round 8
// 647.212 us; speedup vs baseline: 1.1082x; 1.1082x over previous
//
#include <hip/hip_runtime.h>

#define N_NODES 100000
#define N_EDGES 1600000
#define N_GRAPHS 1024
#define HID 128
#define LAYERS 4
#define LN_EPS 1e-5f
#define GTS 136      // ushort row stride for bf16 LDS planes (16B-aligned)
#define HLS 132      // f32 row stride for h stash (2-way bank alias = free)
#define NB_PROJ 50000
#define NB_WCONV 512
#define NBUCK 1563     // ceil(N_NODES/64) buckets of 64 nodes
#define BCAP 2048      // LDS staging capacity (mean 1024, sd 32 -> +32 sigma)
#define EPB 4096       // edges per hist/binscat block (16/thread)
#define NB_BS 391      // ceil(N_EDGES/EPB)

// R2 lesson: device-scope global atomics write ~32B through to HBM EACH
// -> the CSR build's 1.13M atomics (cnt2 + reservations) are pure WT
// traffic. R8: atomic-FREE CSR build. k_hist writes per-(block,bucket)
// counts X coalesced; k_bscan exclusive-scans each bucket's 391 counts
// in XCD-stream order (blk&7 major) so each bucket's layout stays
// stream-segmented (same-XCD blocks write contiguous erec chunks ->
// L2 write merging, the R15/R0 lesson); k_segscan scans bucket totals;
// k_binscat seeds LDS cursors from bucket_base+lexcl directly.
// R7 lesson: holding h rows in VGPRs across phase 2 spilled to scratch
// (+43MB WRITE) -> NU reverted to R6 (LDS h-stash, lowest traffic:
// FETCH 216MB / WRITE 75MB).

typedef __attribute__((ext_vector_type(8))) short bf16x8;
typedef __attribute__((ext_vector_type(4))) float f32x4;
typedef __attribute__((ext_vector_type(2))) float f32x2;

__device__ __forceinline__ unsigned short f2bf(float x) {
    unsigned v = __float_as_uint(x);
    return (unsigned short)((v + 0x7fffu + ((v >> 16) & 1u)) >> 16);
}
__device__ __forceinline__ float bfval(unsigned short u) {
    return __uint_as_float((unsigned)u << 16);
}
// packed-f32 ops (CDNA2+): hipcc never forms these from scalar code.
__device__ __forceinline__ f32x2 pk_fma(f32x2 a, f32x2 b, f32x2 c) {
    f32x2 d;
    asm("v_pk_fma_f32 %0, %1, %2, %3" : "=v"(d) : "v"(a), "v"(b), "v"(c));
    return d;
}
__device__ __forceinline__ f32x2 pk_add(f32x2 a, f32x2 b) {
    f32x2 d;
    asm("v_pk_add_f32 %0, %1, %2" : "=v"(d) : "v"(a), "v"(b));
    return d;
}

// ------- prep: input projection + MFMA weight pre-swizzle ------------
__global__ __launch_bounds__(256) void k_prep(
    const float* __restrict__ x, const float* __restrict__ inW,
    const float* __restrict__ inb, float* __restrict__ h,
    unsigned short* __restrict__ hb,
    const float* __restrict__ w1, const float* __restrict__ w2,
    unsigned short* __restrict__ wf_hi, unsigned short* __restrict__ wf_lo) {
    if (blockIdx.x < NB_PROJ) {
        int idx = blockIdx.x * 256 + threadIdx.x;  // N_NODES*HID exact
        int n = idx >> 7, c = idx & 127;
        const float* xr = x + n * 7;
        float s = inb[c];
#pragma unroll
        for (int k = 0; k < 7; ++k) s += xr[k] * inW[k * HID + c];
        h[idx] = s;
        hb[idx] = f2bf(s);
    } else {
        int idx = (blockIdx.x - NB_PROJ) * 256 + threadIdx.x;  // LAYERS*2*16384
        int wid = idx >> 14;
        int layer = wid >> 1, which = wid & 1;
        int within = idx & 16383;
        int nt = within >> 11;
        int ks = (within >> 9) & 3;
        int ln = (within >> 3) & 63;
        int j = within & 7;
        const float* W = (which ? w2 : w1) + layer * HID * HID;
        int k = ks * 32 + (ln >> 4) * 8 + j;
        int n = nt * 16 + (ln & 15);
        float v = W[k * HID + n];
        unsigned short hi = f2bf(v);
        wf_hi[idx] = hi;
        wf_lo[idx] = f2bf(v - bfval(hi));
    }
}

// ------- CSR build: per-(block,bucket) histogram, coalesced out ------
// Zero global atomics: LDS histogram then one coalesced 6KB row write.
__global__ __launch_bounds__(256) void k_hist(
    const int* __restrict__ ei, int* __restrict__ Xpb) {
    __shared__ int hcnt[NBUCK];
    const int t = threadIdx.x;
    for (int i = t; i < NBUCK; i += 256) hcnt[i] = 0;
    __syncthreads();
    const int e0 = blockIdx.x * EPB;
    const int eend = (e0 + EPB < N_EDGES) ? e0 + EPB : N_EDGES;
#pragma unroll
    for (int k = 0; k < 16; ++k) {
        const int e = e0 + k * 256 + t;
        if (e < eend) atomicAdd(&hcnt[ei[N_EDGES + e] >> 6], 1);
    }
    __syncthreads();
    for (int i = t; i < NBUCK; i += 256)
        Xpb[blockIdx.x * NBUCK + i] = hcnt[i];
}

// ------- CSR build: per-bucket scan of block counts, stream order ----
// One block per bucket. Scan position order = (blk&7 major, blk>>3
// minor): same-XCD blocks (round-robin dispatch) get CONTIGUOUS chunks
// in each bucket -> erec writes merge in one XCD's L2 (R15/R0 lesson).
// Streams 0-6 have 49 blocks, stream 7 has 48 (391 = 8*48+7).
__global__ __launch_bounds__(512) void k_bscan(
    const int* __restrict__ Xpb, int* __restrict__ lexcl,
    int* __restrict__ T) {
    __shared__ int tmp[512];
    const int b = blockIdx.x;
    const int t = threadIdx.x;
    int blk = -1;
    if (t < 343)        blk = (t % 49) * 8 + (t / 49);   // streams 0..6
    else if (t < NB_BS) blk = (t - 343) * 8 + 7;          // stream 7
    const int v = (blk >= 0) ? Xpb[blk * NBUCK + b] : 0;
    tmp[t] = v;
    __syncthreads();
    for (int off = 1; off < 512; off <<= 1) {
        const int u = (t >= off) ? tmp[t - off] : 0;
        __syncthreads();
        tmp[t] += u;
        __syncthreads();
    }
    if (blk >= 0) lexcl[b * NB_BS + blk] = tmp[t] - v;  // exclusive
    if (t == 511) T[b] = tmp[511];                      // bucket total
}

// ------- CSR build: scan bucket totals -> bucket_base ----------------
__global__ __launch_bounds__(1024) void k_segscan(
    const int* __restrict__ T, int* __restrict__ bucket_base,
    int* __restrict__ row_ptr) {
    __shared__ int lsum[1024];
    const int t = threadIdx.x;
    const int b0 = 2 * t, b1 = 2 * t + 1;
    const int u0 = (b0 < NBUCK) ? T[b0] : 0;
    const int u1 = (b1 < NBUCK) ? T[b1] : 0;
    const int v = u0 + u1;
    lsum[t] = v;
    __syncthreads();
    for (int off = 1; off < 1024; off <<= 1) {
        const int u = (t >= off) ? lsum[t - off] : 0;
        __syncthreads();
        lsum[t] += u;
        __syncthreads();
    }
    const int excl = lsum[t] - v;
    if (b0 < NBUCK) bucket_base[b0] = excl;
    if (b1 < NBUCK) bucket_base[b1] = excl + u0;
    if (t == 0) {
        bucket_base[NBUCK] = N_EDGES;
        row_ptr[N_NODES] = N_EDGES;
    }
}

// -------- CSR build pass 1: scatter with precomputed bases -----------
// LDS cursors seeded from bucket_base + lexcl: ZERO global atomics,
// no histogram rebuild. Chunk layout tiles each bucket exactly ->
// erec stays CSR-contiguous at 25.6MB (aliases hb1).
__global__ __launch_bounds__(256) void k_binscat(
    const int* __restrict__ ei, const float* __restrict__ ea,
    const int* __restrict__ bucket_base, const int* __restrict__ lexcl,
    int4* __restrict__ erec) {
    __shared__ int lcur[NBUCK];
    const int t = threadIdx.x;
    const int blk = blockIdx.x;
    for (int i = t; i < NBUCK; i += 256)
        lcur[i] = bucket_base[i] + lexcl[i * NB_BS + blk];
    __syncthreads();
    const int e0 = blk * EPB;
    const int eend = (e0 + EPB < N_EDGES) ? e0 + EPB : N_EDGES;
#pragma unroll
    for (int k = 0; k < 16; ++k) {
        const int e = e0 + k * 256 + t;
        if (e < eend) {
            const int src = ei[e];
            const int dst = ei[N_EDGES + e];
            const float a0 = ea[e * 3 + 0];
            const float a1 = ea[e * 3 + 1];
            const float a2 = ea[e * 3 + 2];
            const int pos = atomicAdd(&lcur[dst >> 6], 1);  // LDS only
            int4 r;
            r.x = src | ((dst & 63) << 20);  // src < 2^17 fits low 20 bits
            r.y = __float_as_int(a0);
            r.z = __float_as_int(a1);
            r.w = __float_as_int(a2);
            erec[pos] = r;
        }
    }
}

// -------- CSR build pass 2: per-bucket LDS sort + row_ptr ------------
__global__ __launch_bounds__(256) void k_bucketsort(
    const int4* __restrict__ erec, const int* __restrict__ bucket_base,
    int* __restrict__ row_ptr, int4* __restrict__ edata) {
    __shared__ int rhist[64];
    __shared__ int lcur[64];
    __shared__ int4 stage[BCAP];
    const int b = blockIdx.x;
    const int nb0 = b << 6;
    const int nrows = (nb0 + 64 <= N_NODES) ? 64 : (N_NODES - nb0);
    const int base = bucket_base[b];
    const int end = bucket_base[b + 1];
    const int cnt = end - base;
    const int t = threadIdx.x;
    if (t < 64) rhist[t] = 0;
    __syncthreads();
    for (int i = t; i < cnt; i += 256)
        atomicAdd(&rhist[(erec[base + i].x >> 20) & 63], 1);
    __syncthreads();
    if (t < 64) {
        const int v = rhist[t];
        int incl = v;
#pragma unroll
        for (int off = 1; off < 64; off <<= 1) {
            const int u = __shfl_up(incl, off);
            if (t >= off) incl += u;
        }
        const int excl = incl - v;
        lcur[t] = excl;
        if (t < nrows) row_ptr[nb0 + t] = base + excl;
    }
    __syncthreads();
    if (cnt <= BCAP) {
        for (int i = t; i < cnt; i += 256) {
            const int4 r = erec[base + i];  // L2-warm re-read
            stage[atomicAdd(&lcur[(r.x >> 20) & 63], 1)] = r;
        }
        __syncthreads();
        for (int i = t; i < cnt; i += 256) {
            int4 r = stage[i];
            r.x &= 0xFFFFF;
            edata[base + i] = r;
        }
    } else {
        // statistically unreachable fallback (cnt mean 1024, sd 32)
        for (int i = t; i < cnt; i += 256) {
            const int4 r = erec[base + i];
            const int pos = base + atomicAdd(&lcur[(r.x >> 20) & 63], 1);
            int4 o = r;
            o.x = r.x & 0xFFFFF;
            edata[pos] = o;
        }
    }
}

// -- phase-1 edge macros (macros only: outlined helpers spill) --------
#define FLUSHSTEP {                                                            \
    if (rcur == 0)      { a0v = acc2; rnext = rp2; }                           \
    else if (rcur == 1) { a1v = acc2; rnext = rp3; }                           \
    else                { a2v = acc2; rnext = 0x7fffffff; }                    \
    acc2[0] = 0.f; acc2[1] = 0.f; ++rcur; }

#define EL(JJ)                                                                 \
    const int s##JJ = __builtin_amdgcn_readlane(cS, j + JJ);                   \
    const unsigned gq##JJ = *(const unsigned*)(hbin + (long)s##JJ * HID + c2);

#define EC(JJ) {                                                               \
    const int gi = t + j + (JJ);                                               \
    while (gi >= rnext) FLUSHSTEP                                              \
    const f32x4 qq = attAB[j + (JJ)];                                          \
    const f32x2 pC = attC[j + (JJ)];                                           \
    f32x2 pA; pA[0] = qq[0]; pA[1] = qq[1];                                    \
    f32x2 pB; pB[0] = qq[2]; pB[1] = qq[3];                                    \
    f32x2 g2; g2[0] = __uint_as_float(gq##JJ << 16);                           \
    g2[1] = __uint_as_float(gq##JJ & 0xffff0000u);                             \
    const f32x2 m2 = pk_fma(pC, ew2v, pk_fma(pB, ew1v, pk_fma(pA, ew0v,        \
                            pk_add(g2, ebv2))));                               \
    f32x2 r2; r2[0] = fmaxf(m2[0], 0.f); r2[1] = fmaxf(m2[1], 0.f);            \
    acc2 = pk_add(acc2, r2); }

// ROW_OUT also stashes the h row in LDS for phase 3's residual
#define ROW_OUT(R, AV) {                                                       \
    const float2 hv = *(const float2*)(h + (long)(nb + (R)) * HID + c2);       \
    *(float2*)&h_lds[(r0 + (R)) * HLS + c2] = hv;                              \
    const float gx = hv.x + (AV)[0], gy = hv.y + (AV)[1];                      \
    const unsigned short hx = f2bf(gx), hy = f2bf(gy);                         \
    const unsigned short lx = f2bf(gx - bfval(hx)), ly = f2bf(gy - bfval(hy)); \
    *(unsigned*)&gt_hi[(r0 + (R)) * GTS + c2] = (unsigned)hx | ((unsigned)hy << 16); \
    *(unsigned*)&gt_lo[(r0 + (R)) * GTS + c2] = (unsigned)lx | ((unsigned)ly << 16); }

#define T1_OUT(CC, NT) {                                                       \
    const float4 bv = *(const float4*)(b1 + (NT) * 16 + q4);                   \
    const float v0 = fmaxf(CC[0] + bv.x, 0.f);                                 \
    const float v1 = fmaxf(CC[1] + bv.y, 0.f);                                 \
    const float v2 = fmaxf(CC[2] + bv.z, 0.f);                                 \
    const float v3 = fmaxf(CC[3] + bv.w, 0.f);                                 \
    const unsigned short h0_ = f2bf(v0), h1_ = f2bf(v1), h2_ = f2bf(v2), h3_ = f2bf(v3); \
    const unsigned short l0_ = f2bf(v0 - bfval(h0_)), l1_ = f2bf(v1 - bfval(h1_)); \
    const unsigned short l2_ = f2bf(v2 - bfval(h2_)), l3_ = f2bf(v3 - bfval(h3_)); \
    *(uint2*)&t1_hi[ln15 * GTS + (NT) * 16 + q4] =                             \
        make_uint2((unsigned)h0_ | ((unsigned)h1_ << 16), (unsigned)h2_ | ((unsigned)h3_ << 16)); \
    *(uint2*)&t1_lo[ln15 * GTS + (NT) * 16 + q4] =                             \
        make_uint2((unsigned)l0_ | ((unsigned)l1_ << 16), (unsigned)l2_ | ((unsigned)l3_ << 16)); }

// ------- fused gather-aggregate + MFMA MLP + residual + layernorm ----
// R6 version: h rows stashed in a dedicated LDS plane during phase 1
// (lowest measured traffic: FETCH 216MB / WRITE 75MB).
__global__ __launch_bounds__(256, 8) void k_node_update(
    const int4* __restrict__ edata, const int* __restrict__ row_ptr,
    const float* __restrict__ eW, const float* __restrict__ eb,
    float* __restrict__ h, const unsigned short* __restrict__ hbin,
    unsigned short* __restrict__ hbout,
    const unsigned short* __restrict__ w1f_hi, const unsigned short* __restrict__ w1f_lo,
    const unsigned short* __restrict__ w2f_hi, const unsigned short* __restrict__ w2f_lo,
    const float* __restrict__ b1, const float* __restrict__ b2,
    const float* __restrict__ gamma, const float* __restrict__ beta) {
    __shared__ __align__(16) unsigned char smem[25856];
    float* stats = (float*)smem;                              // [4][32] f32, phase 3 (aliases gt_hi)
    unsigned short* gt_hi = (unsigned short*)(smem + 0);      // [16][GTS]
    unsigned short* gt_lo = (unsigned short*)(smem + 4352);
    unsigned short* t1_hi = (unsigned short*)(smem + 8704);
    unsigned short* t1_lo = (unsigned short*)(smem + 13056);
    float* h_lds = (float*)(smem + 17408);                    // [16][HLS] f32 stash

    const int wave = threadIdx.x >> 6;
    const int lane = threadIdx.x & 63;
    const int n0 = blockIdx.x * 16;
    const int r0 = wave * 4;
    const int c2 = lane * 2;

    // ---- phase 1: gather-aggregate (EL16/EC16 structure) ----
    // per-wave attr slab in the t1 region (dead until phase 2)
    {
        f32x4* attAB = (f32x4*)(smem + 8704 + wave * 1536);        // (a0,a0,a1,a1)
        f32x2* attC  = (f32x2*)(smem + 8704 + wave * 1536 + 1024); // (a2,a2)
        const f32x2 ew0v = *(const f32x2*)(eW + 0 * HID + c2);
        const f32x2 ew1v = *(const f32x2*)(eW + 1 * HID + c2);
        const f32x2 ew2v = *(const f32x2*)(eW + 2 * HID + c2);
        const f32x2 ebv2 = *(const f32x2*)(eb + c2);
        const int nb = n0 + r0;
        const int rp0 = __builtin_amdgcn_readfirstlane(row_ptr[nb + 0]);
        const int rp1 = __builtin_amdgcn_readfirstlane(row_ptr[nb + 1]);
        const int rp2 = __builtin_amdgcn_readfirstlane(row_ptr[nb + 2]);
        const int rp3 = __builtin_amdgcn_readfirstlane(row_ptr[nb + 3]);
        const int rp4 = __builtin_amdgcn_readfirstlane(row_ptr[nb + 4]);

        f32x2 a0v = {0.f, 0.f}, a1v = {0.f, 0.f};
        f32x2 a2v = {0.f, 0.f}, a3v = {0.f, 0.f};
        f32x2 acc2 = {0.f, 0.f};    // running accumulator (current row)
        int rcur = 0;               // current row index (scalar)
        int rnext = rp1;            // next row boundary

        int4 cE = {0, 0, 0, 0}, nE = {0, 0, 0, 0};
        if (rp0 + lane < rp4) cE = edata[rp0 + lane];
        for (int t = rp0; t < rp4; t += 64) {
            const int cnt = (rp4 - t < 64) ? (rp4 - t) : 64;
            // stage current tile's attrs (duplicated pairs) to LDS
            f32x4 dAB;
            dAB[0] = __int_as_float(cE.y); dAB[1] = dAB[0];
            dAB[2] = __int_as_float(cE.z); dAB[3] = dAB[2];
            f32x2 dC;
            dC[0] = __int_as_float(cE.w); dC[1] = dC[0];
            attAB[lane] = dAB;
            attC[lane] = dC;
            const int cS = cE.x;
            __builtin_amdgcn_wave_barrier();  // ds_write -> ds_read order (same wave, in-order LDS)
            if (t + 64 + lane < rp4)  // prefetch next tile (one 16B load)
                nE = edata[t + 64 + lane];
            int j = 0;
            for (; j + 16 <= cnt; j += 16) {
                EL(0) EL(1) EL(2) EL(3) EL(4) EL(5) EL(6) EL(7)
                EL(8) EL(9) EL(10) EL(11) EL(12) EL(13) EL(14) EL(15)
                EC(0) EC(1) EC(2) EC(3) EC(4) EC(5) EC(6) EC(7)
                EC(8) EC(9) EC(10) EC(11) EC(12) EC(13) EC(14) EC(15)
            }
            for (; j + 4 <= cnt; j += 4) {
                EL(0) EL(1) EL(2) EL(3)
                EC(0) EC(1) EC(2) EC(3)
            }
            for (; j < cnt; ++j) {
                EL(0)
                EC(0)
            }
            __builtin_amdgcn_wave_barrier();  // keep next staging below these reads
            cE = nE;
        }
        // tail: running acc belongs to row rcur; rows after it stay zero
        if (rcur == 0)      a0v = acc2;
        else if (rcur == 1) a1v = acc2;
        else if (rcur == 2) a2v = acc2;
        else                a3v = acc2;
        ROW_OUT(0, a0v)
        ROW_OUT(1, a1v)
        ROW_OUT(2, a2v)
        ROW_OUT(3, a3v)
    }
    __syncthreads();

    const int ln15 = lane & 15;
    const int q8 = (lane >> 4) * 8;
    const int q4 = (lane >> 4) * 4;
    const int nt0 = wave * 2, nt1 = nt0 + 1;

    // ---- phase 2: t1 = relu(gt @ w1 + b1) via MFMA (D[hid][node]) ----
    {
        f32x4 c0 = {0.f, 0.f, 0.f, 0.f};
        f32x4 c1 = {0.f, 0.f, 0.f, 0.f};
#pragma unroll
        for (int ks = 0; ks < 4; ++ks) {
            const bf16x8 bh = *(const bf16x8*)&gt_hi[ln15 * GTS + ks * 32 + q8];
            const bf16x8 bl = *(const bf16x8*)&gt_lo[ln15 * GTS + ks * 32 + q8];
            const bf16x8 a0h = *(const bf16x8*)(w1f_hi + (((nt0 * 4 + ks) * 64 + lane) << 3));
            const bf16x8 a0l = *(const bf16x8*)(w1f_lo + (((nt0 * 4 + ks) * 64 + lane) << 3));
            const bf16x8 a1h = *(const bf16x8*)(w1f_hi + (((nt1 * 4 + ks) * 64 + lane) << 3));
            const bf16x8 a1l = *(const bf16x8*)(w1f_lo + (((nt1 * 4 + ks) * 64 + lane) << 3));
            c0 = __builtin_amdgcn_mfma_f32_16x16x32_bf16(a0h, bh, c0, 0, 0, 0);
            c0 = __builtin_amdgcn_mfma_f32_16x16x32_bf16(a0h, bl, c0, 0, 0, 0);
            c0 = __builtin_amdgcn_mfma_f32_16x16x32_bf16(a0l, bh, c0, 0, 0, 0);
            c1 = __builtin_amdgcn_mfma_f32_16x16x32_bf16(a1h, bh, c1, 0, 0, 0);
            c1 = __builtin_amdgcn_mfma_f32_16x16x32_bf16(a1h, bl, c1, 0, 0, 0);
            c1 = __builtin_amdgcn_mfma_f32_16x16x32_bf16(a1l, bh, c1, 0, 0, 0);
        }
        T1_OUT(c0, nt0)
        T1_OUT(c1, nt1)
    }
    __syncthreads();

    // ---- phase 3: u = h + relu(t1 @ w2 + b2); h from LDS stash ----
    {
        f32x4 c0 = {0.f, 0.f, 0.f, 0.f};
        f32x4 c1 = {0.f, 0.f, 0.f, 0.f};
#pragma unroll
        for (int ks = 0; ks < 4; ++ks) {
            const bf16x8 bh = *(const bf16x8*)&t1_hi[ln15 * GTS + ks * 32 + q8];
            const bf16x8 bl = *(const bf16x8*)&t1_lo[ln15 * GTS + ks * 32 + q8];
            const bf16x8 a0h = *(const bf16x8*)(w2f_hi + (((nt0 * 4 + ks) * 64 + lane) << 3));
            const bf16x8 a0l = *(const bf16x8*)(w2f_lo + (((nt0 * 4 + ks) * 64 + lane) << 3));
            const bf16x8 a1h = *(const bf16x8*)(w2f_hi + (((nt1 * 4 + ks) * 64 + lane) << 3));
            const bf16x8 a1l = *(const bf16x8*)(w2f_lo + (((nt1 * 4 + ks) * 64 + lane) << 3));
            c0 = __builtin_amdgcn_mfma_f32_16x16x32_bf16(a0h, bh, c0, 0, 0, 0);
            c0 = __builtin_amdgcn_mfma_f32_16x16x32_bf16(a0h, bl, c0, 0, 0, 0);
            c0 = __builtin_amdgcn_mfma_f32_16x16x32_bf16(a0l, bh, c0, 0, 0, 0);
            c1 = __builtin_amdgcn_mfma_f32_16x16x32_bf16(a1h, bh, c1, 0, 0, 0);
            c1 = __builtin_amdgcn_mfma_f32_16x16x32_bf16(a1h, bl, c1, 0, 0, 0);
            c1 = __builtin_amdgcn_mfma_f32_16x16x32_bf16(a1l, bh, c1, 0, 0, 0);
        }
        const int row = n0 + ln15;
        const float4 b20 = *(const float4*)(b2 + nt0 * 16 + q4);
        const float4 b21 = *(const float4*)(b2 + nt1 * 16 + q4);
        const float4 hv0 = *(const float4*)&h_lds[ln15 * HLS + nt0 * 16 + q4];
        const float4 hv1 = *(const float4*)&h_lds[ln15 * HLS + nt1 * 16 + q4];
        float4 u0, u1;
        u0.x = hv0.x + fmaxf(c0[0] + b20.x, 0.f);
        u0.y = hv0.y + fmaxf(c0[1] + b20.y, 0.f);
        u0.z = hv0.z + fmaxf(c0[2] + b20.z, 0.f);
        u0.w = hv0.w + fmaxf(c0[3] + b20.w, 0.f);
        u1.x = hv1.x + fmaxf(c1[0] + b21.x, 0.f);
        u1.y = hv1.y + fmaxf(c1[1] + b21.y, 0.f);
        u1.z = hv1.z + fmaxf(c1[2] + b21.z, 0.f);
        u1.w = hv1.w + fmaxf(c1[3] + b21.w, 0.f);
        float s = u0.x + u0.y + u0.z + u0.w + u1.x + u1.y + u1.z + u1.w;
        float s2 = u0.x * u0.x + u0.y * u0.y + u0.z * u0.z + u0.w * u0.w +
                   u1.x * u1.x + u1.y * u1.y + u1.z * u1.z + u1.w * u1.w;
        s += __shfl_xor(s, 16); s2 += __shfl_xor(s2, 16);
        s += __shfl_xor(s, 32); s2 += __shfl_xor(s2, 32);
        if (lane < 16) {
            stats[wave * 32 + lane * 2 + 0] = s;
            stats[wave * 32 + lane * 2 + 1] = s2;
        }
        __syncthreads();
        const float S  = stats[0 * 32 + ln15 * 2] + stats[1 * 32 + ln15 * 2] +
                         stats[2 * 32 + ln15 * 2] + stats[3 * 32 + ln15 * 2];
        const float S2 = stats[0 * 32 + ln15 * 2 + 1] + stats[1 * 32 + ln15 * 2 + 1] +
                         stats[2 * 32 + ln15 * 2 + 1] + stats[3 * 32 + ln15 * 2 + 1];
        const float mu = S * (1.f / HID);
        const float var = S2 * (1.f / HID) - mu * mu;
        const float inv = rsqrtf(var + LN_EPS);
        const float4 gm0 = *(const float4*)(gamma + nt0 * 16 + q4);
        const float4 gm1 = *(const float4*)(gamma + nt1 * 16 + q4);
        const float4 bt0 = *(const float4*)(beta + nt0 * 16 + q4);
        const float4 bt1 = *(const float4*)(beta + nt1 * 16 + q4);
        float4 o0, o1;
        o0.x = (u0.x - mu) * inv * gm0.x + bt0.x;
        o0.y = (u0.y - mu) * inv * gm0.y + bt0.y;
        o0.z = (u0.z - mu) * inv * gm0.z + bt0.z;
        o0.w = (u0.w - mu) * inv * gm0.w + bt0.w;
        o1.x = (u1.x - mu) * inv * gm1.x + bt1.x;
        o1.y = (u1.y - mu) * inv * gm1.y + bt1.y;
        o1.z = (u1.z - mu) * inv * gm1.z + bt1.z;
        o1.w = (u1.w - mu) * inv * gm1.w + bt1.w;
        *(float4*)(h + (long)row * HID + nt0 * 16 + q4) = o0;
        *(float4*)(h + (long)row * HID + nt1 * 16 + q4) = o1;
        *(uint2*)(hbout + (long)row * HID + nt0 * 16 + q4) =
            make_uint2((unsigned)f2bf(o0.x) | ((unsigned)f2bf(o0.y) << 16),
                       (unsigned)f2bf(o0.z) | ((unsigned)f2bf(o0.w) << 16));
        *(uint2*)(hbout + (long)row * HID + nt1 * 16 + q4) =
            make_uint2((unsigned)f2bf(o1.x) | ((unsigned)f2bf(o1.y) << 16),
                       (unsigned)f2bf(o1.z) | ((unsigned)f2bf(o1.w) << 16));
    }
}

// -------- global mean pool: segmented reduction (batch is sorted) ----
__global__ __launch_bounds__(128) void k_pool(
    const float* __restrict__ h, const int* __restrict__ batch,
    float* __restrict__ sums, float* __restrict__ cnt) {
    const int c = threadIdx.x;
    const int n0 = blockIdx.x * 64;
    if (n0 >= N_NODES) return;
    const int nend = min(n0 + 64, N_NODES);
    int cur = batch[n0];
    float acc = 0.f;
    int runlen = 0;
    for (int n = n0; n < nend; ++n) {
        const int b = batch[n];
        if (b != cur) {
            atomicAdd(&sums[(long)cur * HID + c], acc);
            if (c == 0) atomicAdd(&cnt[cur], (float)runlen);
            acc = 0.f;
            runlen = 0;
            cur = b;
        }
        acc += h[(long)n * HID + c];
        ++runlen;
    }
    atomicAdd(&sums[(long)cur * HID + c], acc);
    if (c == 0) atomicAdd(&cnt[cur], (float)runlen);
}

// ---------------- head: 1 block per graph ----------------------------
__global__ __launch_bounds__(128) void k_head(
    const float* __restrict__ sums, const float* __restrict__ cnt,
    const float* __restrict__ fcW1, const float* __restrict__ fcb1,
    const float* __restrict__ fcW2, const float* __restrict__ fcb2,
    const float* __restrict__ fcW3, const float* __restrict__ fcb3,
    float* __restrict__ out) {
    __shared__ float p[HID];
    __shared__ float o1[HID];
    __shared__ float o2[64];
    const int g = blockIdx.x, t = threadIdx.x;
    const float c = fmaxf(cnt[g], 1.0f);
    p[t] = sums[g * HID + t] / c;
    __syncthreads();
    float s = fcb1[t];
    for (int k = 0; k < HID; ++k) s += p[k] * fcW1[k * HID + t];
    o1[t] = fmaxf(s, 0.f);
    __syncthreads();
    if (t < 64) {
        float s2 = fcb2[t];
        for (int k = 0; k < HID; ++k) s2 += o1[k] * fcW2[k * 64 + t];
        o2[t] = fmaxf(s2, 0.f);
    }
    __syncthreads();
    if (t < 64) {
        float v = o2[t] * fcW3[t];
#pragma unroll
        for (int off = 32; off > 0; off >>= 1) v += __shfl_down(v, off);
        if (t == 0) out[g] = v + fcb3[0];
    }
}

extern "C" void kernel_launch(void* const* d_in, const int* in_sizes, int n_in,
                              void* d_out, int out_size, void* d_ws, size_t ws_size,
                              hipStream_t stream) {
    const float* x    = (const float*)d_in[0];
    const int*   ei   = (const int*)d_in[1];
    const float* ea   = (const float*)d_in[2];
    const int*   batch= (const int*)d_in[3];
    const float* inW  = (const float*)d_in[4];
    const float* inb  = (const float*)d_in[5];
    const float* edgeW= (const float*)d_in[6];
    const float* edgeb= (const float*)d_in[7];
    const float* w1   = (const float*)d_in[8];
    const float* b1   = (const float*)d_in[9];
    const float* w2   = (const float*)d_in[10];
    const float* b2   = (const float*)d_in[11];
    const float* gamma= (const float*)d_in[12];
    const float* beta = (const float*)d_in[13];
    const float* fcW1 = (const float*)d_in[14];
    const float* fcb1 = (const float*)d_in[15];
    const float* fcW2 = (const float*)d_in[16];
    const float* fcb2 = (const float*)d_in[17];
    const float* fcW3 = (const float*)d_in[18];
    const float* fcb3 = (const float*)d_in[19];
    float* out = (float*)d_out;

    // workspace layout (16B-aligned blocks first): ~129.5 MB
    int4*  edata = (int4*)d_ws;                                        // 25.6 MB AoS {src,a0,a1,a2}
    float* h     = (float*)(edata + (size_t)N_EDGES);                  // 51.2 MB
    unsigned short* hb0 = (unsigned short*)(h + (size_t)N_NODES * HID);// 25.6 MB
    unsigned short* hb1 = hb0 + (size_t)N_NODES * HID;                 // 25.6 MB
    unsigned short* wf_hi = hb1 + (size_t)N_NODES * HID;               // 256 KB
    unsigned short* wf_lo = wf_hi + LAYERS * 2 * 16384;                // 256 KB
    int*    row_ptr = (int*)(wf_lo + LAYERS * 2 * 16384);              // 100001 ints
    int*    bucket_base = row_ptr + (N_NODES + 1);                     // NBUCK+1 ints
    int*    T       = bucket_base + (NBUCK + 1);                       // NBUCK ints
    // zero-init region (single memset): sums, cnt only
    float*  sums    = (float*)(T + NBUCK);                             // 512 KB
    float*  cnt     = sums + (size_t)N_GRAPHS * HID;
    const size_t zbytes = ((size_t)N_GRAPHS * HID + N_GRAPHS) * sizeof(float);
    // CSR scratch aliases (all dead before their hosts are written):
    // - Xpb/lexcl (2×2.44MB) live in the edata region: consumed by
    //   k_binscat, which completes before k_bucketsort writes edata.
    // - erec (25.6MB) aliases hb1: dead until NU layer 0 writes hbout.
    int*    Xpb     = (int*)edata;                                     // [NB_BS][NBUCK]
    int*    lexcl   = Xpb + (size_t)NB_BS * NBUCK;                     // [NBUCK][NB_BS]
    int4*   erec    = (int4*)hb1;

    hipMemsetAsync(sums, 0, zbytes, stream);

    k_prep<<<NB_PROJ + NB_WCONV, 256, 0, stream>>>(x, inW, inb, h, hb0,
                                                   w1, w2, wf_hi, wf_lo);

    // CSR build (once per launch, reused across 4 layers) - 0 atomics
    k_hist<<<NB_BS, 256, 0, stream>>>(ei, Xpb);
    k_bscan<<<NBUCK, 512, 0, stream>>>(Xpb, lexcl, T);
    k_segscan<<<1, 1024, 0, stream>>>(T, bucket_base, row_ptr);
    k_binscat<<<NB_BS, 256, 0, stream>>>(ei, ea, bucket_base, lexcl, erec);
    k_bucketsort<<<NBUCK, 256, 0, stream>>>(erec, bucket_base, row_ptr, edata);

    unsigned short* hbin = hb0;
    unsigned short* hbout = hb1;
    for (int l = 0; l < LAYERS; ++l) {
        k_node_update<<<N_NODES / 16, 256, 0, stream>>>(
            edata, row_ptr, edgeW + l * 3 * HID, edgeb + l * HID,
            h, hbin, hbout,
            wf_hi + (l * 2 + 0) * 16384, wf_lo + (l * 2 + 0) * 16384,
            wf_hi + (l * 2 + 1) * 16384, wf_lo + (l * 2 + 1) * 16384,
            b1 + l * HID, b2 + l * HID, gamma + l * HID, beta + l * HID);
        unsigned short* tmp = hbin; hbin = hbout; hbout = tmp;
    }
    // final h is in-place in `h` (fp32)

    k_pool<<<(N_NODES + 63) / 64, 128, 0, stream>>>(h, batch, sums, cnt);
    k_head<<<N_GRAPHS, 128, 0, stream>>>(sums, cnt, fcW1, fcb1, fcW2, fcb2,
                                         fcW3, fcb3, out);
}

// Round 9
// 636.696 us; speedup vs baseline: 1.1265x; 1.0165x over previous
//
#include <hip/hip_runtime.h>

#define N_NODES 100000
#define N_EDGES 1600000
#define N_GRAPHS 1024
#define HID 128
#define LAYERS 4
#define LN_EPS 1e-5f
#define GTS 136      // ushort row stride for bf16 LDS planes (16B-aligned)
#define HLS 132      // f32 row stride for h stash (2-way bank alias = free)
#define NB_PROJ 50000
#define NB_WCONV 512
#define NBUCK 1563     // ceil(N_NODES/64) buckets of 64 nodes
#define BCAP 2048      // LDS staging capacity (mean 1024, sd 32 -> +32 sigma)
#define EPB 4096       // edges per hist/binscat block (16/thread)
#define NB_BS 391      // ceil(N_EDGES/EPB)

// R2: global atomics write ~32B through to HBM each -> minimize COUNT
// (R8: CSR build is now atomic-free; saved 41us). R4/R5: NU is not
// VALU-throughput- or pipeline-depth-bound; R6/R7: NU traffic floor is
// FETCH 216MB / WRITE 75MB with LDS h-stash; NU plateaued 110-113us
// across 4 structural variants -> treated as service floor.
// R9: compress the ~199us non-NU tail: (1) k_hist merged into k_prep
// (independent work, was serialized by a launch boundary), (2) k_pool
// +memset deleted -- k_head binary-searches its graph's node range in
// the sorted batch and sums h directly, (3) last NU layer skips the
// hbout write (nothing reads it). 13 launches -> 9.

typedef __attribute__((ext_vector_type(8))) short bf16x8;
typedef __attribute__((ext_vector_type(4))) float f32x4;
typedef __attribute__((ext_vector_type(2))) float f32x2;

__device__ __forceinline__ unsigned short f2bf(float x) {
    unsigned v = __float_as_uint(x);
    return (unsigned short)((v + 0x7fffu + ((v >> 16) & 1u)) >> 16);
}
__device__ __forceinline__ float bfval(unsigned short u) {
    return __uint_as_float((unsigned)u << 16);
}
// packed-f32 ops (CDNA2+): hipcc never forms these from scalar code.
__device__ __forceinline__ f32x2 pk_fma(f32x2 a, f32x2 b, f32x2 c) {
    f32x2 d;
    asm("v_pk_fma_f32 %0, %1, %2, %3" : "=v"(d) : "v"(a), "v"(b), "v"(c));
    return d;
}
__device__ __forceinline__ f32x2 pk_add(f32x2 a, f32x2 b) {
    f32x2 d;
    asm("v_pk_add_f32 %0, %1, %2" : "=v"(d) : "v"(a), "v"(b));
    return d;
}

// -- prep + hist fused: hist blocks FIRST (they gate the CSR chain) --
// proj, weight pre-swizzle, and the per-(block,bucket) histogram are
// mutually independent; fusing removes a full launch-drain boundary.
__global__ __launch_bounds__(256) void k_prep(
    const float* __restrict__ x, const float* __restrict__ inW,
    const float* __restrict__ inb, float* __restrict__ h,
    unsigned short* __restrict__ hb,
    const float* __restrict__ w1, const float* __restrict__ w2,
    unsigned short* __restrict__ wf_hi, unsigned short* __restrict__ wf_lo,
    const int* __restrict__ ei, int* __restrict__ Xpb) {
    const int t = threadIdx.x;
    if (blockIdx.x < NB_BS) {
        // ---- histogram: zero global atomics, coalesced row write ----
        __shared__ int hcnt[NBUCK];
        for (int i = t; i < NBUCK; i += 256) hcnt[i] = 0;
        __syncthreads();
        const int e0 = blockIdx.x * EPB;
        const int eend = (e0 + EPB < N_EDGES) ? e0 + EPB : N_EDGES;
#pragma unroll
        for (int k = 0; k < 16; ++k) {
            const int e = e0 + k * 256 + t;
            if (e < eend) atomicAdd(&hcnt[ei[N_EDGES + e] >> 6], 1);
        }
        __syncthreads();
        for (int i = t; i < NBUCK; i += 256)
            Xpb[blockIdx.x * NBUCK + i] = hcnt[i];
    } else if (blockIdx.x < NB_BS + NB_PROJ) {
        int idx = (blockIdx.x - NB_BS) * 256 + t;  // N_NODES*HID exact
        int n = idx >> 7, c = idx & 127;
        const float* xr = x + n * 7;
        float s = inb[c];
#pragma unroll
        for (int k = 0; k < 7; ++k) s += xr[k] * inW[k * HID + c];
        h[idx] = s;
        hb[idx] = f2bf(s);
    } else {
        int idx = (blockIdx.x - NB_BS - NB_PROJ) * 256 + t;  // LAYERS*2*16384
        int wid = idx >> 14;
        int layer = wid >> 1, which = wid & 1;
        int within = idx & 16383;
        int nt = within >> 11;
        int ks = (within >> 9) & 3;
        int ln = (within >> 3) & 63;
        int j = within & 7;
        const float* W = (which ? w2 : w1) + layer * HID * HID;
        int k = ks * 32 + (ln >> 4) * 8 + j;
        int n = nt * 16 + (ln & 15);
        float v = W[k * HID + n];
        unsigned short hi = f2bf(v);
        wf_hi[idx] = hi;
        wf_lo[idx] = f2bf(v - bfval(hi));
    }
}

// ------- CSR build: per-bucket scan of block counts, stream order ----
// One block per bucket. Scan position order = (blk&7 major, blk>>3
// minor): same-XCD blocks (round-robin dispatch) get CONTIGUOUS chunks
// in each bucket -> erec writes merge in one XCD's L2.
// Streams 0-6 have 49 blocks, stream 7 has 48 (391 = 8*48+7).
__global__ __launch_bounds__(512) void k_bscan(
    const int* __restrict__ Xpb, int* __restrict__ lexcl,
    int* __restrict__ T) {
    __shared__ int tmp[512];
    const int b = blockIdx.x;
    const int t = threadIdx.x;
    int blk = -1;
    if (t < 343)        blk = (t % 49) * 8 + (t / 49);   // streams 0..6
    else if (t < NB_BS) blk = (t - 343) * 8 + 7;          // stream 7
    const int v = (blk >= 0) ? Xpb[blk * NBUCK + b] : 0;
    tmp[t] = v;
    __syncthreads();
    for (int off = 1; off < 512; off <<= 1) {
        const int u = (t >= off) ? tmp[t - off] : 0;
        __syncthreads();
        tmp[t] += u;
        __syncthreads();
    }
    if (blk >= 0) lexcl[b * NB_BS + blk] = tmp[t] - v;  // exclusive
    if (t == 511) T[b] = tmp[511];                      // bucket total
}

// ------- CSR build: scan bucket totals -> bucket_base ----------------
__global__ __launch_bounds__(1024) void k_segscan(
    const int* __restrict__ T, int* __restrict__ bucket_base,
    int* __restrict__ row_ptr) {
    __shared__ int lsum[1024];
    const int t = threadIdx.x;
    const int b0 = 2 * t, b1 = 2 * t + 1;
    const int u0 = (b0 < NBUCK) ? T[b0] : 0;
    const int u1 = (b1 < NBUCK) ? T[b1] : 0;
    const int v = u0 + u1;
    lsum[t] = v;
    __syncthreads();
    for (int off = 1; off < 1024; off <<= 1) {
        const int u = (t >= off) ? lsum[t - off] : 0;
        __syncthreads();
        lsum[t] += u;
        __syncthreads();
    }
    const int excl = lsum[t] - v;
    if (b0 < NBUCK) bucket_base[b0] = excl;
    if (b1 < NBUCK) bucket_base[b1] = excl + u0;
    if (t == 0) {
        bucket_base[NBUCK] = N_EDGES;
        row_ptr[N_NODES] = N_EDGES;
    }
}

// -------- CSR build pass 1: scatter with precomputed bases -----------
// LDS cursors seeded from bucket_base + lexcl: ZERO global atomics.
// Chunk layout tiles each bucket exactly -> erec stays CSR-contiguous
// at 25.6MB (aliases hb1).
__global__ __launch_bounds__(256) void k_binscat(
    const int* __restrict__ ei, const float* __restrict__ ea,
    const int* __restrict__ bucket_base, const int* __restrict__ lexcl,
    int4* __restrict__ erec) {
    __shared__ int lcur[NBUCK];
    const int t = threadIdx.x;
    const int blk = blockIdx.x;
    for (int i = t; i < NBUCK; i += 256)
        lcur[i] = bucket_base[i] + lexcl[i * NB_BS + blk];
    __syncthreads();
    const int e0 = blk * EPB;
    const int eend = (e0 + EPB < N_EDGES) ? e0 + EPB : N_EDGES;
#pragma unroll
    for (int k = 0; k < 16; ++k) {
        const int e = e0 + k * 256 + t;
        if (e < eend) {
            const int src = ei[e];
            const int dst = ei[N_EDGES + e];
            const float a0 = ea[e * 3 + 0];
            const float a1 = ea[e * 3 + 1];
            const float a2 = ea[e * 3 + 2];
            const int pos = atomicAdd(&lcur[dst >> 6], 1);  // LDS only
            int4 r;
            r.x = src | ((dst & 63) << 20);  // src < 2^17 fits low 20 bits
            r.y = __float_as_int(a0);
            r.z = __float_as_int(a1);
            r.w = __float_as_int(a2);
            erec[pos] = r;
        }
    }
}

// -------- CSR build pass 2: per-bucket LDS sort + row_ptr ------------
__global__ __launch_bounds__(256) void k_bucketsort(
    const int4* __restrict__ erec, const int* __restrict__ bucket_base,
    int* __restrict__ row_ptr, int4* __restrict__ edata) {
    __shared__ int rhist[64];
    __shared__ int lcur[64];
    __shared__ int4 stage[BCAP];
    const int b = blockIdx.x;
    const int nb0 = b << 6;
    const int nrows = (nb0 + 64 <= N_NODES) ? 64 : (N_NODES - nb0);
    const int base = bucket_base[b];
    const int end = bucket_base[b + 1];
    const int cnt = end - base;
    const int t = threadIdx.x;
    if (t < 64) rhist[t] = 0;
    __syncthreads();
    for (int i = t; i < cnt; i += 256)
        atomicAdd(&rhist[(erec[base + i].x >> 20) & 63], 1);
    __syncthreads();
    if (t < 64) {
        const int v = rhist[t];
        int incl = v;
#pragma unroll
        for (int off = 1; off < 64; off <<= 1) {
            const int u = __shfl_up(incl, off);
            if (t >= off) incl += u;
        }
        const int excl = incl - v;
        lcur[t] = excl;
        if (t < nrows) row_ptr[nb0 + t] = base + excl;
    }
    __syncthreads();
    if (cnt <= BCAP) {
        for (int i = t; i < cnt; i += 256) {
            const int4 r = erec[base + i];  // L2-warm re-read
            stage[atomicAdd(&lcur[(r.x >> 20) & 63], 1)] = r;
        }
        __syncthreads();
        for (int i = t; i < cnt; i += 256) {
            int4 r = stage[i];
            r.x &= 0xFFFFF;
            edata[base + i] = r;
        }
    } else {
        // statistically unreachable fallback (cnt mean 1024, sd 32)
        for (int i = t; i < cnt; i += 256) {
            const int4 r = erec[base + i];
            const int pos = base + atomicAdd(&lcur[(r.x >> 20) & 63], 1);
            int4 o = r;
            o.x = r.x & 0xFFFFF;
            edata[pos] = o;
        }
    }
}

// -- phase-1 edge macros (macros only: outlined helpers spill) --------
#define FLUSHSTEP {                                                            \
    if (rcur == 0)      { a0v = acc2; rnext = rp2; }                           \
    else if (rcur == 1) { a1v = acc2; rnext = rp3; }                           \
    else                { a2v = acc2; rnext = 0x7fffffff; }                    \
    acc2[0] = 0.f; acc2[1] = 0.f; ++rcur; }

#define EL(JJ)                                                                 \
    const int s##JJ = __builtin_amdgcn_readlane(cS, j + JJ);                   \
    const unsigned gq##JJ = *(const unsigned*)(hbin + (long)s##JJ * HID + c2);

#define EC(JJ) {                                                               \
    const int gi = t + j + (JJ);                                               \
    while (gi >= rnext) FLUSHSTEP                                              \
    const f32x4 qq = attAB[j + (JJ)];                                          \
    const f32x2 pC = attC[j + (JJ)];                                           \
    f32x2 pA; pA[0] = qq[0]; pA[1] = qq[1];                                    \
    f32x2 pB; pB[0] = qq[2]; pB[1] = qq[3];                                    \
    f32x2 g2; g2[0] = __uint_as_float(gq##JJ << 16);                           \
    g2[1] = __uint_as_float(gq##JJ & 0xffff0000u);                             \
    const f32x2 m2 = pk_fma(pC, ew2v, pk_fma(pB, ew1v, pk_fma(pA, ew0v,        \
                            pk_add(g2, ebv2))));                               \
    f32x2 r2; r2[0] = fmaxf(m2[0], 0.f); r2[1] = fmaxf(m2[1], 0.f);            \
    acc2 = pk_add(acc2, r2); }

// ROW_OUT also stashes the h row in LDS for phase 3's residual
#define ROW_OUT(R, AV) {                                                       \
    const float2 hv = *(const float2*)(h + (long)(nb + (R)) * HID + c2);       \
    *(float2*)&h_lds[(r0 + (R)) * HLS + c2] = hv;                              \
    const float gx = hv.x + (AV)[0], gy = hv.y + (AV)[1];                      \
    const unsigned short hx = f2bf(gx), hy = f2bf(gy);                         \
    const unsigned short lx = f2bf(gx - bfval(hx)), ly = f2bf(gy - bfval(hy)); \
    *(unsigned*)&gt_hi[(r0 + (R)) * GTS + c2] = (unsigned)hx | ((unsigned)hy << 16); \
    *(unsigned*)&gt_lo[(r0 + (R)) * GTS + c2] = (unsigned)lx | ((unsigned)ly << 16); }

#define T1_OUT(CC, NT) {                                                       \
    const float4 bv = *(const float4*)(b1 + (NT) * 16 + q4);                   \
    const float v0 = fmaxf(CC[0] + bv.x, 0.f);                                 \
    const float v1 = fmaxf(CC[1] + bv.y, 0.f);                                 \
    const float v2 = fmaxf(CC[2] + bv.z, 0.f);                                 \
    const float v3 = fmaxf(CC[3] + bv.w, 0.f);                                 \
    const unsigned short h0_ = f2bf(v0), h1_ = f2bf(v1), h2_ = f2bf(v2), h3_ = f2bf(v3); \
    const unsigned short l0_ = f2bf(v0 - bfval(h0_)), l1_ = f2bf(v1 - bfval(h1_)); \
    const unsigned short l2_ = f2bf(v2 - bfval(h2_)), l3_ = f2bf(v3 - bfval(h3_)); \
    *(uint2*)&t1_hi[ln15 * GTS + (NT) * 16 + q4] =                             \
        make_uint2((unsigned)h0_ | ((unsigned)h1_ << 16), (unsigned)h2_ | ((unsigned)h3_ << 16)); \
    *(uint2*)&t1_lo[ln15 * GTS + (NT) * 16 + q4] =                             \
        make_uint2((unsigned)l0_ | ((unsigned)l1_ << 16), (unsigned)l2_ | ((unsigned)l3_ << 16)); }

// ------- fused gather-aggregate + MFMA MLP + residual + layernorm ----
// R6/R8 structure (lowest traffic). write_hb=0 on the last layer skips
// the hbout store (nothing reads hbin after layer 3): -25.6MB write.
__global__ __launch_bounds__(256, 8) void k_node_update(
    const int4* __restrict__ edata, const int* __restrict__ row_ptr,
    const float* __restrict__ eW, const float* __restrict__ eb,
    float* __restrict__ h, const unsigned short* __restrict__ hbin,
    unsigned short* __restrict__ hbout,
    const unsigned short* __restrict__ w1f_hi, const unsigned short* __restrict__ w1f_lo,
    const unsigned short* __restrict__ w2f_hi, const unsigned short* __restrict__ w2f_lo,
    const float* __restrict__ b1, const float* __restrict__ b2,
    const float* __restrict__ gamma, const float* __restrict__ beta,
    const int write_hb) {
    __shared__ __align__(16) unsigned char smem[25856];
    float* stats = (float*)smem;                              // [4][32] f32, phase 3 (aliases gt_hi)
    unsigned short* gt_hi = (unsigned short*)(smem + 0);      // [16][GTS]
    unsigned short* gt_lo = (unsigned short*)(smem + 4352);
    unsigned short* t1_hi = (unsigned short*)(smem + 8704);
    unsigned short* t1_lo = (unsigned short*)(smem + 13056);
    float* h_lds = (float*)(smem + 17408);                    // [16][HLS] f32 stash

    const int wave = threadIdx.x >> 6;
    const int lane = threadIdx.x & 63;
    const int n0 = blockIdx.x * 16;
    const int r0 = wave * 4;
    const int c2 = lane * 2;

    // ---- phase 1: gather-aggregate (EL16/EC16 structure) ----
    // per-wave attr slab in the t1 region (dead until phase 2)
    {
        f32x4* attAB = (f32x4*)(smem + 8704 + wave * 1536);        // (a0,a0,a1,a1)
        f32x2* attC  = (f32x2*)(smem + 8704 + wave * 1536 + 1024); // (a2,a2)
        const f32x2 ew0v = *(const f32x2*)(eW + 0 * HID + c2);
        const f32x2 ew1v = *(const f32x2*)(eW + 1 * HID + c2);
        const f32x2 ew2v = *(const f32x2*)(eW + 2 * HID + c2);
        const f32x2 ebv2 = *(const f32x2*)(eb + c2);
        const int nb = n0 + r0;
        const int rp0 = __builtin_amdgcn_readfirstlane(row_ptr[nb + 0]);
        const int rp1 = __builtin_amdgcn_readfirstlane(row_ptr[nb + 1]);
        const int rp2 = __builtin_amdgcn_readfirstlane(row_ptr[nb + 2]);
        const int rp3 = __builtin_amdgcn_readfirstlane(row_ptr[nb + 3]);
        const int rp4 = __builtin_amdgcn_readfirstlane(row_ptr[nb + 4]);

        f32x2 a0v = {0.f, 0.f}, a1v = {0.f, 0.f};
        f32x2 a2v = {0.f, 0.f}, a3v = {0.f, 0.f};
        f32x2 acc2 = {0.f, 0.f};    // running accumulator (current row)
        int rcur = 0;               // current row index (scalar)
        int rnext = rp1;            // next row boundary

        int4 cE = {0, 0, 0, 0}, nE = {0, 0, 0, 0};
        if (rp0 + lane < rp4) cE = edata[rp0 + lane];
        for (int t = rp0; t < rp4; t += 64) {
            const int cnt = (rp4 - t < 64) ? (rp4 - t) : 64;
            // stage current tile's attrs (duplicated pairs) to LDS
            f32x4 dAB;
            dAB[0] = __int_as_float(cE.y); dAB[1] = dAB[0];
            dAB[2] = __int_as_float(cE.z); dAB[3] = dAB[2];
            f32x2 dC;
            dC[0] = __int_as_float(cE.w); dC[1] = dC[0];
            attAB[lane] = dAB;
            attC[lane] = dC;
            const int cS = cE.x;
            __builtin_amdgcn_wave_barrier();  // ds_write -> ds_read order (same wave, in-order LDS)
            if (t + 64 + lane < rp4)  // prefetch next tile (one 16B load)
                nE = edata[t + 64 + lane];
            int j = 0;
            for (; j + 16 <= cnt; j += 16) {
                EL(0) EL(1) EL(2) EL(3) EL(4) EL(5) EL(6) EL(7)
                EL(8) EL(9) EL(10) EL(11) EL(12) EL(13) EL(14) EL(15)
                EC(0) EC(1) EC(2) EC(3) EC(4) EC(5) EC(6) EC(7)
                EC(8) EC(9) EC(10) EC(11) EC(12) EC(13) EC(14) EC(15)
            }
            for (; j + 4 <= cnt; j += 4) {
                EL(0) EL(1) EL(2) EL(3)
                EC(0) EC(1) EC(2) EC(3)
            }
            for (; j < cnt; ++j) {
                EL(0)
                EC(0)
            }
            __builtin_amdgcn_wave_barrier();  // keep next staging below these reads
            cE = nE;
        }
        // tail: running acc belongs to row rcur; rows after it stay zero
        if (rcur == 0)      a0v = acc2;
        else if (rcur == 1) a1v = acc2;
        else if (rcur == 2) a2v = acc2;
        else                a3v = acc2;
        ROW_OUT(0, a0v)
        ROW_OUT(1, a1v)
        ROW_OUT(2, a2v)
        ROW_OUT(3, a3v)
    }
    __syncthreads();

    const int ln15 = lane & 15;
    const int q8 = (lane >> 4) * 8;
    const int q4 = (lane >> 4) * 4;
    const int nt0 = wave * 2, nt1 = nt0 + 1;

    // ---- phase 2: t1 = relu(gt @ w1 + b1) via MFMA (D[hid][node]) ----
    {
        f32x4 c0 = {0.f, 0.f, 0.f, 0.f};
        f32x4 c1 = {0.f, 0.f, 0.f, 0.f};
#pragma unroll
        for (int ks = 0; ks < 4; ++ks) {
            const bf16x8 bh = *(const bf16x8*)&gt_hi[ln15 * GTS + ks * 32 + q8];
            const bf16x8 bl = *(const bf16x8*)&gt_lo[ln15 * GTS + ks * 32 + q8];
            const bf16x8 a0h = *(const bf16x8*)(w1f_hi + (((nt0 * 4 + ks) * 64 + lane) << 3));
            const bf16x8 a0l = *(const bf16x8*)(w1f_lo + (((nt0 * 4 + ks) * 64 + lane) << 3));
            const bf16x8 a1h = *(const bf16x8*)(w1f_hi + (((nt1 * 4 + ks) * 64 + lane) << 3));
            const bf16x8 a1l = *(const bf16x8*)(w1f_lo + (((nt1 * 4 + ks) * 64 + lane) << 3));
            c0 = __builtin_amdgcn_mfma_f32_16x16x32_bf16(a0h, bh, c0, 0, 0, 0);
            c0 = __builtin_amdgcn_mfma_f32_16x16x32_bf16(a0h, bl, c0, 0, 0, 0);
            c0 = __builtin_amdgcn_mfma_f32_16x16x32_bf16(a0l, bh, c0, 0, 0, 0);
            c1 = __builtin_amdgcn_mfma_f32_16x16x32_bf16(a1h, bh, c1, 0, 0, 0);
            c1 = __builtin_amdgcn_mfma_f32_16x16x32_bf16(a1h, bl, c1, 0, 0, 0);
            c1 = __builtin_amdgcn_mfma_f32_16x16x32_bf16(a1l, bh, c1, 0, 0, 0);
        }
        T1_OUT(c0, nt0)
        T1_OUT(c1, nt1)
    }
    __syncthreads();

    // ---- phase 3: u = h + relu(t1 @ w2 + b2); h from LDS stash ----
    {
        f32x4 c0 = {0.f, 0.f, 0.f, 0.f};
        f32x4 c1 = {0.f, 0.f, 0.f, 0.f};
#pragma unroll
        for (int ks = 0; ks < 4; ++ks) {
            const bf16x8 bh = *(const bf16x8*)&t1_hi[ln15 * GTS + ks * 32 + q8];
            const bf16x8 bl = *(const bf16x8*)&t1_lo[ln15 * GTS + ks * 32 + q8];
            const bf16x8 a0h = *(const bf16x8*)(w2f_hi + (((nt0 * 4 + ks) * 64 + lane) << 3));
            const bf16x8 a0l = *(const bf16x8*)(w2f_lo + (((nt0 * 4 + ks) * 64 + lane) << 3));
            const bf16x8 a1h = *(const bf16x8*)(w2f_hi + (((nt1 * 4 + ks) * 64 + lane) << 3));
            const bf16x8 a1l = *(const bf16x8*)(w2f_lo + (((nt1 * 4 + ks) * 64 + lane) << 3));
            c0 = __builtin_amdgcn_mfma_f32_16x16x32_bf16(a0h, bh, c0, 0, 0, 0);
            c0 = __builtin_amdgcn_mfma_f32_16x16x32_bf16(a0h, bl, c0, 0, 0, 0);
            c0 = __builtin_amdgcn_mfma_f32_16x16x32_bf16(a0l, bh, c0, 0, 0, 0);
            c1 = __builtin_amdgcn_mfma_f32_16x16x32_bf16(a1h, bh, c1, 0, 0, 0);
            c1 = __builtin_amdgcn_mfma_f32_16x16x32_bf16(a1h, bl, c1, 0, 0, 0);
            c1 = __builtin_amdgcn_mfma_f32_16x16x32_bf16(a1l, bh, c1, 0, 0, 0);
        }
        const int row = n0 + ln15;
        const float4 b20 = *(const float4*)(b2 + nt0 * 16 + q4);
        const float4 b21 = *(const float4*)(b2 + nt1 * 16 + q4);
        const float4 hv0 = *(const float4*)&h_lds[ln15 * HLS + nt0 * 16 + q4];
        const float4 hv1 = *(const float4*)&h_lds[ln15 * HLS + nt1 * 16 + q4];
        float4 u0, u1;
        u0.x = hv0.x + fmaxf(c0[0] + b20.x, 0.f);
        u0.y = hv0.y + fmaxf(c0[1] + b20.y, 0.f);
        u0.z = hv0.z + fmaxf(c0[2] + b20.z, 0.f);
        u0.w = hv0.w + fmaxf(c0[3] + b20.w, 0.f);
        u1.x = hv1.x + fmaxf(c1[0] + b21.x, 0.f);
        u1.y = hv1.y + fmaxf(c1[1] + b21.y, 0.f);
        u1.z = hv1.z + fmaxf(c1[2] + b21.z, 0.f);
        u1.w = hv1.w + fmaxf(c1[3] + b21.w, 0.f);
        float s = u0.x + u0.y + u0.z + u0.w + u1.x + u1.y + u1.z + u1.w;
        float s2 = u0.x * u0.x + u0.y * u0.y + u0.z * u0.z + u0.w * u0.w +
                   u1.x * u1.x + u1.y * u1.y + u1.z * u1.z + u1.w * u1.w;
        s += __shfl_xor(s, 16); s2 += __shfl_xor(s2, 16);
        s += __shfl_xor(s, 32); s2 += __shfl_xor(s2, 32);
        if (lane < 16) {
            stats[wave * 32 + lane * 2 + 0] = s;
            stats[wave * 32 + lane * 2 + 1] = s2;
        }
        __syncthreads();
        const float S  = stats[0 * 32 + ln15 * 2] + stats[1 * 32 + ln15 * 2] +
                         stats[2 * 32 + ln15 * 2] + stats[3 * 32 + ln15 * 2];
        const float S2 = stats[0 * 32 + ln15 * 2 + 1] + stats[1 * 32 + ln15 * 2 + 1] +
                         stats[2 * 32 + ln15 * 2 + 1] + stats[3 * 32 + ln15 * 2 + 1];
        const float mu = S * (1.f / HID);
        const float var = S2 * (1.f / HID) - mu * mu;
        const float inv = rsqrtf(var + LN_EPS);
        const float4 gm0 = *(const float4*)(gamma + nt0 * 16 + q4);
        const float4 gm1 = *(const float4*)(gamma + nt1 * 16 + q4);
        const float4 bt0 = *(const float4*)(beta + nt0 * 16 + q4);
        const float4 bt1 = *(const float4*)(beta + nt1 * 16 + q4);
        float4 o0, o1;
        o0.x = (u0.x - mu) * inv * gm0.x + bt0.x;
        o0.y = (u0.y - mu) * inv * gm0.y + bt0.y;
        o0.z = (u0.z - mu) * inv * gm0.z + bt0.z;
        o0.w = (u0.w - mu) * inv * gm0.w + bt0.w;
        o1.x = (u1.x - mu) * inv * gm1.x + bt1.x;
        o1.y = (u1.y - mu) * inv * gm1.y + bt1.y;
        o1.z = (u1.z - mu) * inv * gm1.z + bt1.z;
        o1.w = (u1.w - mu) * inv * gm1.w + bt1.w;
        *(float4*)(h + (long)row * HID + nt0 * 16 + q4) = o0;
        *(float4*)(h + (long)row * HID + nt1 * 16 + q4) = o1;
        if (write_hb) {
            *(uint2*)(hbout + (long)row * HID + nt0 * 16 + q4) =
                make_uint2((unsigned)f2bf(o0.x) | ((unsigned)f2bf(o0.y) << 16),
                           (unsigned)f2bf(o0.z) | ((unsigned)f2bf(o0.w) << 16));
            *(uint2*)(hbout + (long)row * HID + nt1 * 16 + q4) =
                make_uint2((unsigned)f2bf(o1.x) | ((unsigned)f2bf(o1.y) << 16),
                           (unsigned)f2bf(o1.z) | ((unsigned)f2bf(o1.w) << 16));
        }
    }
}

// ------- head: 1 block per graph; pool fused via binary search -------
// batch is sorted: block g finds its node range [lo,hi) with two
// lower_bounds (uniform, L2-broadcast reads), sums h rows directly.
// Deletes k_pool, sums/cnt arrays, their atomics, and the memset.
__global__ __launch_bounds__(128) void k_head(
    const float* __restrict__ h, const int* __restrict__ batch,
    const float* __restrict__ fcW1, const float* __restrict__ fcb1,
    const float* __restrict__ fcW2, const float* __restrict__ fcb2,
    const float* __restrict__ fcW3, const float* __restrict__ fcb3,
    float* __restrict__ out) {
    __shared__ float p[HID];
    __shared__ float o1[HID];
    __shared__ float o2[64];
    const int g = blockIdx.x, t = threadIdx.x;
    // lower_bound(batch, g) and lower_bound(batch, g+1) - wave-uniform
    int lo = 0, hi = N_NODES;
    while (lo < hi) {
        const int m = (lo + hi) >> 1;
        if (batch[m] < g) lo = m + 1; else hi = m;
    }
    const int start = lo;
    hi = N_NODES;
    while (lo < hi) {
        const int m = (lo + hi) >> 1;
        if (batch[m] < g + 1) lo = m + 1; else hi = m;
    }
    const int end = lo;
    float acc = 0.f;
    for (int n = start; n < end; ++n) acc += h[(long)n * HID + t];
    const float c = fmaxf((float)(end - start), 1.0f);
    p[t] = acc / c;
    __syncthreads();
    float s = fcb1[t];
    for (int k = 0; k < HID; ++k) s += p[k] * fcW1[k * HID + t];
    o1[t] = fmaxf(s, 0.f);
    __syncthreads();
    if (t < 64) {
        float s2 = fcb2[t];
        for (int k = 0; k < HID; ++k) s2 += o1[k] * fcW2[k * 64 + t];
        o2[t] = fmaxf(s2, 0.f);
    }
    __syncthreads();
    if (t < 64) {
        float v = o2[t] * fcW3[t];
#pragma unroll
        for (int off = 32; off > 0; off >>= 1) v += __shfl_down(v, off);
        if (t == 0) out[g] = v + fcb3[0];
    }
}

extern "C" void kernel_launch(void* const* d_in, const int* in_sizes, int n_in,
                              void* d_out, int out_size, void* d_ws, size_t ws_size,
                              hipStream_t stream) {
    const float* x    = (const float*)d_in[0];
    const int*   ei   = (const int*)d_in[1];
    const float* ea   = (const float*)d_in[2];
    const int*   batch= (const int*)d_in[3];
    const float* inW  = (const float*)d_in[4];
    const float* inb  = (const float*)d_in[5];
    const float* edgeW= (const float*)d_in[6];
    const float* edgeb= (const float*)d_in[7];
    const float* w1   = (const float*)d_in[8];
    const float* b1   = (const float*)d_in[9];
    const float* w2   = (const float*)d_in[10];
    const float* b2   = (const float*)d_in[11];
    const float* gamma= (const float*)d_in[12];
    const float* beta = (const float*)d_in[13];
    const float* fcW1 = (const float*)d_in[14];
    const float* fcb1 = (const float*)d_in[15];
    const float* fcW2 = (const float*)d_in[16];
    const float* fcb2 = (const float*)d_in[17];
    const float* fcW3 = (const float*)d_in[18];
    const float* fcb3 = (const float*)d_in[19];
    float* out = (float*)d_out;

    // workspace layout (16B-aligned blocks first): ~129 MB
    int4*  edata = (int4*)d_ws;                                        // 25.6 MB AoS {src,a0,a1,a2}
    float* h     = (float*)(edata + (size_t)N_EDGES);                  // 51.2 MB
    unsigned short* hb0 = (unsigned short*)(h + (size_t)N_NODES * HID);// 25.6 MB
    unsigned short* hb1 = hb0 + (size_t)N_NODES * HID;                 // 25.6 MB
    unsigned short* wf_hi = hb1 + (size_t)N_NODES * HID;               // 256 KB
    unsigned short* wf_lo = wf_hi + LAYERS * 2 * 16384;                // 256 KB
    int*    row_ptr = (int*)(wf_lo + LAYERS * 2 * 16384);              // 100001 ints
    int*    bucket_base = row_ptr + (N_NODES + 1);                     // NBUCK+1 ints
    int*    T       = bucket_base + (NBUCK + 1);                       // NBUCK ints
    // CSR scratch aliases (all dead before their hosts are written):
    // - Xpb/lexcl (2x2.44MB) live in the edata region: consumed by
    //   k_binscat, which completes before k_bucketsort writes edata.
    // - erec (25.6MB) aliases hb1: dead until NU layer 0 writes hbout.
    int*    Xpb     = (int*)edata;                                     // [NB_BS][NBUCK]
    int*    lexcl   = Xpb + (size_t)NB_BS * NBUCK;                     // [NBUCK][NB_BS]
    int4*   erec    = (int4*)hb1;

    // prep + hist fused (hist blocks first); no memset needed anywhere
    k_prep<<<NB_BS + NB_PROJ + NB_WCONV, 256, 0, stream>>>(
        x, inW, inb, h, hb0, w1, w2, wf_hi, wf_lo, ei, Xpb);

    // CSR build (once per launch, reused across 4 layers) - 0 atomics
    k_bscan<<<NBUCK, 512, 0, stream>>>(Xpb, lexcl, T);
    k_segscan<<<1, 1024, 0, stream>>>(T, bucket_base, row_ptr);
    k_binscat<<<NB_BS, 256, 0, stream>>>(ei, ea, bucket_base, lexcl, erec);
    k_bucketsort<<<NBUCK, 256, 0, stream>>>(erec, bucket_base, row_ptr, edata);

    unsigned short* hbin = hb0;
    unsigned short* hbout = hb1;
    for (int l = 0; l < LAYERS; ++l) {
        k_node_update<<<N_NODES / 16, 256, 0, stream>>>(
            edata, row_ptr, edgeW + l * 3 * HID, edgeb + l * HID,
            h, hbin, hbout,
            wf_hi + (l * 2 + 0) * 16384, wf_lo + (l * 2 + 0) * 16384,
            wf_hi + (l * 2 + 1) * 16384, wf_lo + (l * 2 + 1) * 16384,
            b1 + l * HID, b2 + l * HID, gamma + l * HID, beta + l * HID,
            (l < LAYERS - 1) ? 1 : 0);
        unsigned short* tmp = hbin; hbin = hbout; hbout = tmp;
    }
    // final h is in-place in `h` (fp32)

    k_head<<<N_GRAPHS, 128, 0, stream>>>(h, batch, fcW1, fcb1, fcW2, fcb2,
                                         fcW3, fcb3, out);
}